// Round 2
// baseline (316.120 us; speedup 1.0000x reference)
//
#include <hip/hip_runtime.h>
#include <hip/hip_bf16.h>

// DeepViT re-attention, fused flash-style two-pass.
//  k0 convert3 : x, w_qkv, w_out fp32 -> bf16 (ws)
//  k1 gemm<1>  : qkv = x @ w_qkv^T (bf16 MFMA); scatter q(scaled)/k/vT bf16
//  k2 passA    : per (b,h,i): softmax stats (m, l) in exp2 domain, j-split x2
//  k2b merge   : combine j-split partials -> (m, 1/l)
//  k3 passB    : recompute S', p, 8x8 head mix + LN (in-lane), PV -> inner bf16
//                1024 thr / 16 waves per block for occupancy (VGPR cap = 16 waves/CU)
//  k4 gemm<0>  : out = inner @ w_out^T + b_out (fp32)

typedef __attribute__((ext_vector_type(8))) short bfx8;
typedef __attribute__((ext_vector_type(4))) float f32x4;
typedef unsigned short u16;

#define QSCALE 0.18033688011112042f  /* (1/8) * log2(e) */

static __device__ inline u16 f2bf(float f) {
  union { float f; unsigned u; } cv; cv.f = f;
  unsigned u = cv.u;
  u += 0x7fffu + ((u >> 16) & 1u);   // RNE
  return (u16)(u >> 16);
}

// ---------------- k0: fp32 -> bf16 converts ----------------
__global__ __launch_bounds__(256) void convert3(
    const float* __restrict__ x, const float* __restrict__ wq,
    const float* __restrict__ wo,
    u16* __restrict__ xb, u16* __restrict__ wqb, u16* __restrict__ wob) {
  int e = (blockIdx.x * 256 + threadIdx.x) * 4;
  const float* src; u16* dst; int off;
  if (e < 2097152)      { src = x;  dst = xb;  off = e; }
  else if (e < 2883584) { src = wq; dst = wqb; off = e - 2097152; }
  else                  { src = wo; dst = wob; off = e - 2883584; }
  float4 v = *(const float4*)&src[off];
  ushort4 o; o.x = f2bf(v.x); o.y = f2bf(v.y); o.z = f2bf(v.z); o.w = f2bf(v.w);
  *(ushort4*)&dst[off] = o;
}

// ---------------- k1/k4: bf16 GEMM, C = A @ B^T ----------------
template<int EPI>
__global__ __launch_bounds__(256) void gemm_k(
    const u16* __restrict__ A, const u16* __restrict__ B, int K,
    float* __restrict__ outf, const float* __restrict__ bias,
    u16* __restrict__ qb, u16* __restrict__ kb, u16* __restrict__ vtb) {
  __shared__ u16 As[128 * 32];
  __shared__ u16 Bs[128 * 32];
  const int t = threadIdx.x, lane = t & 63;
  const int wm = (t >> 6) >> 1, wn = (t >> 6) & 1;
  const int m0 = blockIdx.y * 128, n0 = blockIdx.x * 128;
  const int li = lane & 15, lg = lane >> 4;
  const int rowA = t >> 2, kb8 = (t & 3) * 8;
  f32x4 acc[4][4] = {};
  for (int k0 = 0; k0 < K; k0 += 32) {
    __syncthreads();
    *(bfx8*)&As[rowA * 32 + kb8]        = *(const bfx8*)&A[(size_t)(m0 + rowA) * K + k0 + kb8];
    *(bfx8*)&As[(rowA + 64) * 32 + kb8] = *(const bfx8*)&A[(size_t)(m0 + rowA + 64) * K + k0 + kb8];
    *(bfx8*)&Bs[rowA * 32 + kb8]        = *(const bfx8*)&B[(size_t)(n0 + rowA) * K + k0 + kb8];
    *(bfx8*)&Bs[(rowA + 64) * 32 + kb8] = *(const bfx8*)&B[(size_t)(n0 + rowA + 64) * K + k0 + kb8];
    __syncthreads();
    bfx8 af[4], bf_[4];
#pragma unroll
    for (int mi = 0; mi < 4; mi++)
      af[mi] = *(const bfx8*)&As[(wm * 64 + mi * 16 + li) * 32 + lg * 8];
#pragma unroll
    for (int ni = 0; ni < 4; ni++)
      bf_[ni] = *(const bfx8*)&Bs[(wn * 64 + ni * 16 + li) * 32 + lg * 8];
#pragma unroll
    for (int mi = 0; mi < 4; mi++)
#pragma unroll
      for (int ni = 0; ni < 4; ni++)
        acc[mi][ni] = __builtin_amdgcn_mfma_f32_16x16x32_bf16(af[mi], bf_[ni], acc[mi][ni], 0, 0, 0);
  }
#pragma unroll
  for (int mi = 0; mi < 4; mi++) {
#pragma unroll
    for (int ni = 0; ni < 4; ni++) {
      const int nc  = n0 + wn * 64 + ni * 16 + li;
      const int mrb = m0 + wm * 64 + mi * 16 + lg * 4;
      if (EPI == 0) {
        const float bv = bias[nc];
#pragma unroll
        for (int r = 0; r < 4; r++)
          outf[(size_t)(mrb + r) * 512 + nc] = acc[mi][ni][r] + bv;
      } else {
        const int part = nc >> 9, within = nc & 511;
        const int h = within >> 6, d = within & 63;
        const int bb = mrb >> 11, ii = mrb & 2047;
        if (part == 0) {
#pragma unroll
          for (int r = 0; r < 4; r++)
            qb[(((size_t)bb * 8 + h) * 2048 + ii + r) * 64 + d] = f2bf(acc[mi][ni][r] * QSCALE);
        } else if (part == 1) {
#pragma unroll
          for (int r = 0; r < 4; r++)
            kb[(((size_t)bb * 8 + h) * 2048 + ii + r) * 64 + d] = f2bf(acc[mi][ni][r]);
        } else {
          ushort4 u;
          u.x = f2bf(acc[mi][ni][0]); u.y = f2bf(acc[mi][ni][1]);
          u.z = f2bf(acc[mi][ni][2]); u.w = f2bf(acc[mi][ni][3]);
          *(ushort4*)&vtb[(((size_t)bb * 8 + h) * 64 + d) * 2048 + ii] = u;
        }
      }
    }
  }
}

// ---------------- k2: softmax stats (m, l), j-split x2 ----------------
// grid (32, 16, 2): x = i-tile-of-64, y = b*8+h, z = j-split. 4 waves.
__global__ __launch_bounds__(256) void passA(
    const u16* __restrict__ qb, const u16* __restrict__ kb,
    float2* __restrict__ statp) {
  const int t = threadIdx.x, lane = t & 63, w = t >> 6;
  const int bh = blockIdx.y, js = blockIdx.z;
  const int i0 = blockIdx.x * 64 + w * 16;
  const int li = lane & 15, lg = lane >> 4;
  const u16* Qh = qb + ((size_t)bh * 2048 + i0 + li) * 64;
  const u16* Kb = kb + (size_t)bh * 2048 * 64;
  const bfx8 q0 = *(const bfx8*)&Qh[lg * 8];
  const bfx8 q1 = *(const bfx8*)&Qh[32 + lg * 8];
  float m = -1e30f, l = 0.f;
  const int jbeg = js * 1024, jend = jbeg + 1024;
  for (int j0 = jbeg; j0 < jend; j0 += 16) {
    const u16* Kh = Kb + (size_t)(j0 + li) * 64;
    bfx8 k0 = *(const bfx8*)&Kh[lg * 8];
    bfx8 k1 = *(const bfx8*)&Kh[32 + lg * 8];
    f32x4 s = {0.f, 0.f, 0.f, 0.f};
    s = __builtin_amdgcn_mfma_f32_16x16x32_bf16(k0, q0, s, 0, 0, 0);
    s = __builtin_amdgcn_mfma_f32_16x16x32_bf16(k1, q1, s, 0, 0, 0);
    float mt = fmaxf(fmaxf(s[0], s[1]), fmaxf(s[2], s[3]));
    float mn = fmaxf(m, mt);
    l = fmaf(l, exp2f(m - mn),
             exp2f(s[0] - mn) + exp2f(s[1] - mn) + exp2f(s[2] - mn) + exp2f(s[3] - mn));
    m = mn;
  }
  for (int off = 16; off < 64; off <<= 1) {
    float mo = __shfl_xor(m, off, 64);
    float lo = __shfl_xor(l, off, 64);
    float mn = fmaxf(m, mo);
    l = l * exp2f(m - mn) + lo * exp2f(mo - mn);
    m = mn;
  }
  if (lane < 16) statp[((size_t)js * 16 + bh) * 2048 + i0 + li] = make_float2(m, l);
}

// ---------------- k2b: merge the 2 j-split partials ----------------
__global__ __launch_bounds__(256) void mergeStats(
    const float2* __restrict__ statp, float2* __restrict__ stats) {
  int idx = blockIdx.x * 256 + threadIdx.x;  // bh*2048 + i
  float2 a = statp[idx], c = statp[32768 + idx];
  float m = fmaxf(a.x, c.x);
  float l = a.y * exp2f(a.x - m) + c.y * exp2f(c.x - m);
  stats[idx] = make_float2(m, 1.f / l);
}

// ---------------- k3: pass B — normalize, head-mix, LN, PV ----------------
// grid (128, 2): x = i-tile-of-16, y = b. 1024 thr = 16 waves.
// Phase 1 (wave w = j-slab of 16 within 256-wide macro tile): S'^T all 8 heads
//   -> p in-lane -> 8x8 mix + LN -> A'' bf16 to LDS (XOR-swizzled).
// Phase 2: wave w -> head w&7, j-half w>>3. Pair-reduce pacc via LDS at end.
__global__ __launch_bounds__(1024) void passB(
    const u16* __restrict__ qb, const u16* __restrict__ kb,
    const u16* __restrict__ vtb, const float2* __restrict__ stats,
    const float* __restrict__ Wmix, const float* __restrict__ lng,
    const float* __restrict__ lnb, u16* __restrict__ inner) {
  __shared__ __align__(16) u16 A2[8 * 16 * 256];  // 64KB [g][i][j], j XOR-swizzled
  const int t = threadIdx.x, lane = t & 63, w = t >> 6;
  const int b = blockIdx.y, i0 = blockIdx.x * 16;
  const int li = lane & 15, lg = lane >> 4;
  const int swz = (li & 7) << 3;
  const int hd = w & 7, jh = w >> 3;

  float wm_[8][8], lng_[8], lnb_[8];
#pragma unroll
  for (int h = 0; h < 8; h++)
#pragma unroll
    for (int g = 0; g < 8; g++) wm_[h][g] = Wmix[h * 8 + g];
#pragma unroll
  for (int g = 0; g < 8; g++) { lng_[g] = lng[g]; lnb_[g] = lnb[g]; }

  bfx8 qf[8][2];
  float2 st[8];
#pragma unroll
  for (int h = 0; h < 8; h++) {
    const u16* Qh = qb + (((size_t)(b * 8 + h)) * 2048 + i0 + li) * 64;
    qf[h][0] = *(const bfx8*)&Qh[lg * 8];
    qf[h][1] = *(const bfx8*)&Qh[32 + lg * 8];
    st[h] = stats[((size_t)(b * 8 + h)) * 2048 + i0 + li];
  }
  f32x4 pacc[4] = {};
  for (int jm = 0; jm < 2048; jm += 256) {
    const int j0 = jm + w * 16;
    float p[8][4];
#pragma unroll
    for (int h = 0; h < 8; h++) {
      const u16* Kh = kb + (((size_t)(b * 8 + h)) * 2048 + j0 + li) * 64;
      bfx8 k0 = *(const bfx8*)&Kh[lg * 8];
      bfx8 k1 = *(const bfx8*)&Kh[32 + lg * 8];
      f32x4 s = {0.f, 0.f, 0.f, 0.f};
      s = __builtin_amdgcn_mfma_f32_16x16x32_bf16(k0, qf[h][0], s, 0, 0, 0);
      s = __builtin_amdgcn_mfma_f32_16x16x32_bf16(k1, qf[h][1], s, 0, 0, 0);
#pragma unroll
      for (int r = 0; r < 4; r++) p[h][r] = exp2f(s[r] - st[h].x) * st[h].y;
    }
    float av[8][4];
#pragma unroll
    for (int r = 0; r < 4; r++) {
      float a_[8]; float sum = 0.f, sumsq = 0.f;
#pragma unroll
      for (int g = 0; g < 8; g++) {
        float acc = 0.f;
#pragma unroll
        for (int h = 0; h < 8; h++) acc = fmaf(p[h][r], wm_[h][g], acc);
        a_[g] = acc; sum += acc; sumsq = fmaf(acc, acc, sumsq);
      }
      const float mu = sum * 0.125f;
      const float var = fmaf(sumsq, 0.125f, -mu * mu);
      const float rs = rsqrtf(var + 1e-5f);
#pragma unroll
      for (int g = 0; g < 8; g++)
        av[g][r] = fmaf((a_[g] - mu) * rs, lng_[g], lnb_[g]);
    }
    {
      const int jsw = (w * 16 + lg * 4) ^ swz;   // 4 consecutive j per lane
#pragma unroll
      for (int g = 0; g < 8; g++) {
        ushort4 u;
        u.x = f2bf(av[g][0]); u.y = f2bf(av[g][1]);
        u.z = f2bf(av[g][2]); u.w = f2bf(av[g][3]);
        *(ushort4*)&A2[(g * 16 + li) * 256 + jsw] = u;
      }
    }
    __syncthreads();
    {
      const u16* Vh = vtb + ((size_t)(b * 8 + hd)) * 64 * 2048;
#pragma unroll
      for (int kc = 0; kc < 4; kc++) {
        const int jc = jh * 128 + kc * 32 + lg * 8;
        bfx8 af = *(const bfx8*)&A2[(hd * 16 + li) * 256 + (jc ^ swz)];
#pragma unroll
        for (int nd = 0; nd < 4; nd++) {
          bfx8 vf = *(const bfx8*)&Vh[(size_t)(nd * 16 + li) * 2048 + jm + jc];
          pacc[nd] = __builtin_amdgcn_mfma_f32_16x16x32_bf16(af, vf, pacc[nd], 0, 0, 0);
        }
      }
    }
    __syncthreads();
  }
  // pair-reduce pacc across (w, w+8) via LDS, then store
  float* red = (float*)A2;
  if (w >= 8) {
    const int base = ((w - 8) * 64 + lane) * 16;
#pragma unroll
    for (int nd = 0; nd < 4; nd++)
#pragma unroll
      for (int r = 0; r < 4; r++) red[base + nd * 4 + r] = pacc[nd][r];
  }
  __syncthreads();
  if (w < 8) {
    const int base = (w * 64 + lane) * 16;
#pragma unroll
    for (int nd = 0; nd < 4; nd++) {
#pragma unroll
      for (int r = 0; r < 4; r++) {
        float v = pacc[nd][r] + red[base + nd * 4 + r];
        inner[((size_t)b * 2048 + i0 + lg * 4 + r) * 512 + hd * 64 + nd * 16 + li] = f2bf(v);
      }
    }
  }
}

// ---------------- host ----------------
extern "C" void kernel_launch(void* const* d_in, const int* in_sizes, int n_in,
                              void* d_out, int out_size, void* d_ws, size_t ws_size,
                              hipStream_t stream) {
  const float* x      = (const float*)d_in[0];
  const float* w_qkv  = (const float*)d_in[1];
  const float* reattn = (const float*)d_in[2];
  const float* ln_g   = (const float*)d_in[3];
  const float* ln_b   = (const float*)d_in[4];
  const float* w_out  = (const float*)d_in[5];
  const float* b_out  = (const float*)d_in[6];
  float* out = (float*)d_out;
  char* ws = (char*)d_ws;
  u16*    xb    = (u16*)(ws + 0);          // 4096x512 bf16
  u16*    wqb   = (u16*)(ws + 4194304);    // 1536x512 bf16
  u16*    wob   = (u16*)(ws + 5767168);    // 512x512 bf16
  u16*    qbf   = (u16*)(ws + 6291456);    // [2,8,2048,64] bf16 (scaled)
  u16*    kbf   = (u16*)(ws + 10485760);   // [2,8,2048,64] bf16
  u16*    vtb   = (u16*)(ws + 14680064);   // [2,8,64,2048] bf16
  float2* stats = (float2*)(ws + 18874368);// [2,8,2048] (m, 1/l)
  u16*    inner = (u16*)(ws + 19136512);   // 4096x512 bf16
  float2* statp = (float2*)(ws + 23330816);// [2][2,8,2048] raw (m, l) partials

  convert3<<<3072, 256, 0, stream>>>(x, w_qkv, w_out, xb, wqb, wob);
  gemm_k<1><<<dim3(12, 32), 256, 0, stream>>>(xb, wqb, 512, nullptr, nullptr, qbf, kbf, vtb);
  passA<<<dim3(32, 16, 2), 256, 0, stream>>>(qbf, kbf, statp);
  mergeStats<<<128, 256, 0, stream>>>(statp, stats);
  passB<<<dim3(128, 2), 1024, 0, stream>>>(qbf, kbf, vtb, stats, reattn, ln_g, ln_b, inner);
  gemm_k<0><<<dim3(4, 32), 256, 0, stream>>>(inner, wob, 512, out, b_out, nullptr, nullptr, nullptr);
}

// Round 3
// 310.729 us; speedup vs baseline: 1.0174x; 1.0174x over previous
//
#include <hip/hip_runtime.h>
#include <hip/hip_bf16.h>

// DeepViT re-attention, fused flash-style two-pass.
//  k0 convert3 : x, w_qkv, w_out fp32 -> bf16 (ws)
//  k1 gemm<1>  : qkv = x @ w_qkv^T (bf16 MFMA); scatter q(scaled)/k/vT bf16
//  (memset)    : zero inner_f32 accumulator (reuses xb/wqb region)
//  k2 passA    : per (b,h,i): softmax stats (m, l) in exp2 domain, j-split x2
//  k2b merge   : combine j-split partials -> (m, 1/l)
//  k3 passB    : recompute S', p, 8x8 head mix + LN (in-lane), PV partial,
//                atomicAdd f32 -> inner_f32. grid (128,2,2) = 512 blocks,
//                512 thr, __launch_bounds__(512,4): 2 blocks/CU, VGPR<=128.
//  k3b convert : inner_f32 -> bf16
//  k4 gemm<0>  : out = inner @ w_out^T + b_out (fp32)

typedef __attribute__((ext_vector_type(8))) short bfx8;
typedef __attribute__((ext_vector_type(4))) float f32x4;
typedef unsigned short u16;

#define QSCALE 0.18033688011112042f  /* (1/8) * log2(e) */

static __device__ inline u16 f2bf(float f) {
  union { float f; unsigned u; } cv; cv.f = f;
  unsigned u = cv.u;
  u += 0x7fffu + ((u >> 16) & 1u);   // RNE
  return (u16)(u >> 16);
}

// ---------------- k0: fp32 -> bf16 converts ----------------
__global__ __launch_bounds__(256) void convert3(
    const float* __restrict__ x, const float* __restrict__ wq,
    const float* __restrict__ wo,
    u16* __restrict__ xb, u16* __restrict__ wqb, u16* __restrict__ wob) {
  int e = (blockIdx.x * 256 + threadIdx.x) * 4;
  const float* src; u16* dst; int off;
  if (e < 2097152)      { src = x;  dst = xb;  off = e; }
  else if (e < 2883584) { src = wq; dst = wqb; off = e - 2097152; }
  else                  { src = wo; dst = wob; off = e - 2883584; }
  float4 v = *(const float4*)&src[off];
  ushort4 o; o.x = f2bf(v.x); o.y = f2bf(v.y); o.z = f2bf(v.z); o.w = f2bf(v.w);
  *(ushort4*)&dst[off] = o;
}

// ---------------- k1/k4: bf16 GEMM, C = A @ B^T ----------------
template<int EPI>
__global__ __launch_bounds__(256) void gemm_k(
    const u16* __restrict__ A, const u16* __restrict__ B, int K,
    float* __restrict__ outf, const float* __restrict__ bias,
    u16* __restrict__ qb, u16* __restrict__ kb, u16* __restrict__ vtb) {
  __shared__ u16 As[128 * 32];
  __shared__ u16 Bs[128 * 32];
  const int t = threadIdx.x, lane = t & 63;
  const int wm = (t >> 6) >> 1, wn = (t >> 6) & 1;
  const int m0 = blockIdx.y * 128, n0 = blockIdx.x * 128;
  const int li = lane & 15, lg = lane >> 4;
  const int rowA = t >> 2, kb8 = (t & 3) * 8;
  f32x4 acc[4][4] = {};
  for (int k0 = 0; k0 < K; k0 += 32) {
    __syncthreads();
    *(bfx8*)&As[rowA * 32 + kb8]        = *(const bfx8*)&A[(size_t)(m0 + rowA) * K + k0 + kb8];
    *(bfx8*)&As[(rowA + 64) * 32 + kb8] = *(const bfx8*)&A[(size_t)(m0 + rowA + 64) * K + k0 + kb8];
    *(bfx8*)&Bs[rowA * 32 + kb8]        = *(const bfx8*)&B[(size_t)(n0 + rowA) * K + k0 + kb8];
    *(bfx8*)&Bs[(rowA + 64) * 32 + kb8] = *(const bfx8*)&B[(size_t)(n0 + rowA + 64) * K + k0 + kb8];
    __syncthreads();
    bfx8 af[4], bf_[4];
#pragma unroll
    for (int mi = 0; mi < 4; mi++)
      af[mi] = *(const bfx8*)&As[(wm * 64 + mi * 16 + li) * 32 + lg * 8];
#pragma unroll
    for (int ni = 0; ni < 4; ni++)
      bf_[ni] = *(const bfx8*)&Bs[(wn * 64 + ni * 16 + li) * 32 + lg * 8];
#pragma unroll
    for (int mi = 0; mi < 4; mi++)
#pragma unroll
      for (int ni = 0; ni < 4; ni++)
        acc[mi][ni] = __builtin_amdgcn_mfma_f32_16x16x32_bf16(af[mi], bf_[ni], acc[mi][ni], 0, 0, 0);
  }
#pragma unroll
  for (int mi = 0; mi < 4; mi++) {
#pragma unroll
    for (int ni = 0; ni < 4; ni++) {
      const int nc  = n0 + wn * 64 + ni * 16 + li;
      const int mrb = m0 + wm * 64 + mi * 16 + lg * 4;
      if (EPI == 0) {
        const float bv = bias[nc];
#pragma unroll
        for (int r = 0; r < 4; r++)
          outf[(size_t)(mrb + r) * 512 + nc] = acc[mi][ni][r] + bv;
      } else {
        const int part = nc >> 9, within = nc & 511;
        const int h = within >> 6, d = within & 63;
        const int bb = mrb >> 11, ii = mrb & 2047;
        if (part == 0) {
#pragma unroll
          for (int r = 0; r < 4; r++)
            qb[(((size_t)bb * 8 + h) * 2048 + ii + r) * 64 + d] = f2bf(acc[mi][ni][r] * QSCALE);
        } else if (part == 1) {
#pragma unroll
          for (int r = 0; r < 4; r++)
            kb[(((size_t)bb * 8 + h) * 2048 + ii + r) * 64 + d] = f2bf(acc[mi][ni][r]);
        } else {
          ushort4 u;
          u.x = f2bf(acc[mi][ni][0]); u.y = f2bf(acc[mi][ni][1]);
          u.z = f2bf(acc[mi][ni][2]); u.w = f2bf(acc[mi][ni][3]);
          *(ushort4*)&vtb[(((size_t)bb * 8 + h) * 64 + d) * 2048 + ii] = u;
        }
      }
    }
  }
}

// ---------------- k2: softmax stats (m, l), j-split x2 ----------------
__global__ __launch_bounds__(256) void passA(
    const u16* __restrict__ qb, const u16* __restrict__ kb,
    float2* __restrict__ statp) {
  const int t = threadIdx.x, lane = t & 63, w = t >> 6;
  const int bh = blockIdx.y, js = blockIdx.z;
  const int i0 = blockIdx.x * 64 + w * 16;
  const int li = lane & 15, lg = lane >> 4;
  const u16* Qh = qb + ((size_t)bh * 2048 + i0 + li) * 64;
  const u16* Kb = kb + (size_t)bh * 2048 * 64;
  const bfx8 q0 = *(const bfx8*)&Qh[lg * 8];
  const bfx8 q1 = *(const bfx8*)&Qh[32 + lg * 8];
  float m = -1e30f, l = 0.f;
  const int jbeg = js * 1024, jend = jbeg + 1024;
  for (int j0 = jbeg; j0 < jend; j0 += 16) {
    const u16* Kh = Kb + (size_t)(j0 + li) * 64;
    bfx8 k0 = *(const bfx8*)&Kh[lg * 8];
    bfx8 k1 = *(const bfx8*)&Kh[32 + lg * 8];
    f32x4 s = {0.f, 0.f, 0.f, 0.f};
    s = __builtin_amdgcn_mfma_f32_16x16x32_bf16(k0, q0, s, 0, 0, 0);
    s = __builtin_amdgcn_mfma_f32_16x16x32_bf16(k1, q1, s, 0, 0, 0);
    float mt = fmaxf(fmaxf(s[0], s[1]), fmaxf(s[2], s[3]));
    float mn = fmaxf(m, mt);
    l = fmaf(l, exp2f(m - mn),
             exp2f(s[0] - mn) + exp2f(s[1] - mn) + exp2f(s[2] - mn) + exp2f(s[3] - mn));
    m = mn;
  }
  for (int off = 16; off < 64; off <<= 1) {
    float mo = __shfl_xor(m, off, 64);
    float lo = __shfl_xor(l, off, 64);
    float mn = fmaxf(m, mo);
    l = l * exp2f(m - mn) + lo * exp2f(mo - mn);
    m = mn;
  }
  if (lane < 16) statp[((size_t)js * 16 + bh) * 2048 + i0 + li] = make_float2(m, l);
}

// ---------------- k2b: merge the 2 j-split partials ----------------
__global__ __launch_bounds__(256) void mergeStats(
    const float2* __restrict__ statp, float2* __restrict__ stats) {
  int idx = blockIdx.x * 256 + threadIdx.x;  // bh*2048 + i
  float2 a = statp[idx], c = statp[32768 + idx];
  float m = fmaxf(a.x, c.x);
  float l = a.y * exp2f(a.x - m) + c.y * exp2f(c.x - m);
  stats[idx] = make_float2(m, 1.f / l);
}

// ---------------- k3: pass B — normalize, head-mix, LN, PV partial ----------------
// grid (128, 2, 2): x = i-tile-of-16, y = b, z = j-split. 512 thr = 8 waves.
// Phase 1 (wave w = j-slab of 16 in 128-wide macro tile): S'^T all 8 heads ->
//   p in-lane -> 8x8 mix + LN -> A'' bf16 to LDS (XOR-swizzled).
// Phase 2 (wave w = head w): PV MFMAs over the 128-j macro tile.
// Epilogue: atomicAdd partial into zeroed inner_f32 (2 commutative adds).
__global__ __launch_bounds__(512, 4) void passB(
    const u16* __restrict__ qb, const u16* __restrict__ kb,
    const u16* __restrict__ vtb, const float2* __restrict__ stats,
    const float* __restrict__ Wmix, const float* __restrict__ lng,
    const float* __restrict__ lnb, float* __restrict__ innerF) {
  __shared__ __align__(16) u16 A2[8 * 16 * 128];  // 32KB [g][i][j], j XOR-swizzled
  const int t = threadIdx.x, lane = t & 63, w = t >> 6;
  const int b = blockIdx.y, i0 = blockIdx.x * 16;
  const int li = lane & 15, lg = lane >> 4;
  const int swz = (li & 7) << 3;

  float wm_[8][8], lng_[8], lnb_[8];
#pragma unroll
  for (int h = 0; h < 8; h++)
#pragma unroll
    for (int g = 0; g < 8; g++) wm_[h][g] = Wmix[h * 8 + g];
#pragma unroll
  for (int g = 0; g < 8; g++) { lng_[g] = lng[g]; lnb_[g] = lnb[g]; }

  bfx8 qf[8][2];
  float2 st[8];
#pragma unroll
  for (int h = 0; h < 8; h++) {
    const u16* Qh = qb + (((size_t)(b * 8 + h)) * 2048 + i0 + li) * 64;
    qf[h][0] = *(const bfx8*)&Qh[lg * 8];
    qf[h][1] = *(const bfx8*)&Qh[32 + lg * 8];
    st[h] = stats[((size_t)(b * 8 + h)) * 2048 + i0 + li];
  }
  f32x4 pacc[4] = {};
  const int jmb = blockIdx.z * 1024;
  for (int jm = jmb; jm < jmb + 1024; jm += 128) {
    const int j0 = jm + w * 16;
    float p[8][4];
#pragma unroll
    for (int h = 0; h < 8; h++) {
      const u16* Kh = kb + (((size_t)(b * 8 + h)) * 2048 + j0 + li) * 64;
      bfx8 k0 = *(const bfx8*)&Kh[lg * 8];
      bfx8 k1 = *(const bfx8*)&Kh[32 + lg * 8];
      f32x4 s = {0.f, 0.f, 0.f, 0.f};
      s = __builtin_amdgcn_mfma_f32_16x16x32_bf16(k0, qf[h][0], s, 0, 0, 0);
      s = __builtin_amdgcn_mfma_f32_16x16x32_bf16(k1, qf[h][1], s, 0, 0, 0);
#pragma unroll
      for (int r = 0; r < 4; r++) p[h][r] = exp2f(s[r] - st[h].x) * st[h].y;
    }
    float av[8][4];
#pragma unroll
    for (int r = 0; r < 4; r++) {
      float a_[8]; float sum = 0.f, sumsq = 0.f;
#pragma unroll
      for (int g = 0; g < 8; g++) {
        float acc = 0.f;
#pragma unroll
        for (int h = 0; h < 8; h++) acc = fmaf(p[h][r], wm_[h][g], acc);
        a_[g] = acc; sum += acc; sumsq = fmaf(acc, acc, sumsq);
      }
      const float mu = sum * 0.125f;
      const float var = fmaf(sumsq, 0.125f, -mu * mu);
      const float rs = rsqrtf(var + 1e-5f);
#pragma unroll
      for (int g = 0; g < 8; g++)
        av[g][r] = fmaf((a_[g] - mu) * rs, lng_[g], lnb_[g]);
    }
    {
      const int jsw = (w * 16 + lg * 4) ^ swz;   // 4 consecutive j per lane
#pragma unroll
      for (int g = 0; g < 8; g++) {
        ushort4 u;
        u.x = f2bf(av[g][0]); u.y = f2bf(av[g][1]);
        u.z = f2bf(av[g][2]); u.w = f2bf(av[g][3]);
        *(ushort4*)&A2[(g * 16 + li) * 128 + jsw] = u;
      }
    }
    __syncthreads();
    {
      const u16* Vh = vtb + ((size_t)(b * 8 + w)) * 64 * 2048;
#pragma unroll
      for (int kc = 0; kc < 4; kc++) {
        const int jr = (kc * 32 + lg * 8) ^ swz;
        bfx8 af = *(const bfx8*)&A2[(w * 16 + li) * 128 + jr];
#pragma unroll
        for (int nd = 0; nd < 4; nd++) {
          bfx8 vf = *(const bfx8*)&Vh[(size_t)(nd * 16 + li) * 2048 + jm + kc * 32 + lg * 8];
          pacc[nd] = __builtin_amdgcn_mfma_f32_16x16x32_bf16(af, vf, pacc[nd], 0, 0, 0);
        }
      }
    }
    __syncthreads();
  }
#pragma unroll
  for (int nd = 0; nd < 4; nd++)
#pragma unroll
    for (int r = 0; r < 4; r++)
      atomicAdd(&innerF[((size_t)b * 2048 + i0 + lg * 4 + r) * 512 + w * 64 + nd * 16 + li],
                pacc[nd][r]);
}

// ---------------- k3b: inner f32 -> bf16 ----------------
__global__ __launch_bounds__(256) void convertInner(
    const float* __restrict__ inF, u16* __restrict__ outB) {
  int e = (blockIdx.x * 256 + threadIdx.x) * 4;
  float4 v = *(const float4*)&inF[e];
  ushort4 o; o.x = f2bf(v.x); o.y = f2bf(v.y); o.z = f2bf(v.z); o.w = f2bf(v.w);
  *(ushort4*)&outB[e] = o;
}

// ---------------- host ----------------
extern "C" void kernel_launch(void* const* d_in, const int* in_sizes, int n_in,
                              void* d_out, int out_size, void* d_ws, size_t ws_size,
                              hipStream_t stream) {
  const float* x      = (const float*)d_in[0];
  const float* w_qkv  = (const float*)d_in[1];
  const float* reattn = (const float*)d_in[2];
  const float* ln_g   = (const float*)d_in[3];
  const float* ln_b   = (const float*)d_in[4];
  const float* w_out  = (const float*)d_in[5];
  const float* b_out  = (const float*)d_in[6];
  float* out = (float*)d_out;
  char* ws = (char*)d_ws;
  // ws layout (bytes), total 22.3 MB (proven budget >= 23.9 MB):
  //  [0, 8388608)       : xb (0..4 MB) + wqb (4..5.75 MB) during k0/k1;
  //                       then inner_f32 [2,2048,512] f32 (zeroed after k1)
  u16*    xb    = (u16*)(ws + 0);
  u16*    wqb   = (u16*)(ws + 4194304);
  float*  innerF= (float*)(ws + 0);
  u16*    qbf   = (u16*)(ws + 8388608);    // [2,8,2048,64] bf16 (scaled)
  u16*    kbf   = (u16*)(ws + 12582912);   // [2,8,2048,64] bf16
  u16*    vtb   = (u16*)(ws + 16777216);   // [2,8,64,2048] bf16
  float2* stats = (float2*)(ws + 20971520);// [2,8,2048] (m, 1/l)
  float2* statp = (float2*)(ws + 21233664);// [2][2,8,2048] raw (m, l)
  u16*    wob   = (u16*)(ws + 21757952);   // 512x512 bf16
  u16*    innerB= (u16*)(ws + 8388608);    // reuses qbf after passB

  convert3<<<3072, 256, 0, stream>>>(x, w_qkv, w_out, xb, wqb, wob);
  gemm_k<1><<<dim3(12, 32), 256, 0, stream>>>(xb, wqb, 512, nullptr, nullptr, qbf, kbf, vtb);
  hipMemsetAsync(innerF, 0, 8388608, stream);  // also frees xb/wqb region
  passA<<<dim3(32, 16, 2), 256, 0, stream>>>(qbf, kbf, statp);
  mergeStats<<<128, 256, 0, stream>>>(statp, stats);
  passB<<<dim3(128, 2, 2), 512, 0, stream>>>(qbf, kbf, vtb, stats, reattn, ln_g, ln_b, innerF);
  convertInner<<<2048, 256, 0, stream>>>(innerF, innerB);
  gemm_k<0><<<dim3(4, 32), 256, 0, stream>>>(innerB, wob, 512, out, b_out, nullptr, nullptr, nullptr);
}

// Round 4
// 292.718 us; speedup vs baseline: 1.0799x; 1.0615x over previous
//
#include <hip/hip_runtime.h>
#include <hip/hip_bf16.h>

// DeepViT re-attention, fused flash-style two-pass.
//  k0 convert3 : x, w_qkv, w_out fp32 -> bf16 (ws)
//  k1 gemm<1>  : qkv = x @ w_qkv^T (bf16 MFMA); scatter q(scaled)/k/vT bf16
//  (memset)    : zero inner_f32 accumulator (reuses xb/wqb region)
//  k2 passA    : per (b,h,i): softmax stats (m, l) in exp2 domain, j-split x2
//  k2b merge   : combine j-split partials -> (m, 1/l)
//  k3 passB    : recompute S', p, 8x8 head mix + LN (in-lane), PV partial,
//                atomicAdd f32 -> inner_f32. grid (128,2,2)=512 blocks, 512 thr.
//                NOTE: no min-occupancy hint — (512,4) made the compiler cap
//                VGPR at 64 and spill (R2/R3: FETCH 250-320MB). Natural alloc
//                is 128 VGPR = 2 blocks/CU anyway.
//  k3b convert : inner_f32 -> bf16
//  k4 gemm<0>  : out = inner @ w_out^T + b_out (fp32)

typedef __attribute__((ext_vector_type(8))) short bfx8;
typedef __attribute__((ext_vector_type(4))) float f32x4;
typedef unsigned short u16;

#define QSCALE 0.18033688011112042f  /* (1/8) * log2(e) */

static __device__ inline u16 f2bf(float f) {
  union { float f; unsigned u; } cv; cv.f = f;
  unsigned u = cv.u;
  u += 0x7fffu + ((u >> 16) & 1u);   // RNE
  return (u16)(u >> 16);
}

// ---------------- k0: fp32 -> bf16 converts ----------------
__global__ __launch_bounds__(256) void convert3(
    const float* __restrict__ x, const float* __restrict__ wq,
    const float* __restrict__ wo,
    u16* __restrict__ xb, u16* __restrict__ wqb, u16* __restrict__ wob) {
  int e = (blockIdx.x * 256 + threadIdx.x) * 4;
  const float* src; u16* dst; int off;
  if (e < 2097152)      { src = x;  dst = xb;  off = e; }
  else if (e < 2883584) { src = wq; dst = wqb; off = e - 2097152; }
  else                  { src = wo; dst = wob; off = e - 2883584; }
  float4 v = *(const float4*)&src[off];
  ushort4 o; o.x = f2bf(v.x); o.y = f2bf(v.y); o.z = f2bf(v.z); o.w = f2bf(v.w);
  *(ushort4*)&dst[off] = o;
}

// ---------------- k1/k4: bf16 GEMM, C = A @ B^T ----------------
template<int EPI>
__global__ __launch_bounds__(256) void gemm_k(
    const u16* __restrict__ A, const u16* __restrict__ B, int K,
    float* __restrict__ outf, const float* __restrict__ bias,
    u16* __restrict__ qb, u16* __restrict__ kb, u16* __restrict__ vtb) {
  __shared__ u16 As[128 * 32];
  __shared__ u16 Bs[128 * 32];
  const int t = threadIdx.x, lane = t & 63;
  const int wm = (t >> 6) >> 1, wn = (t >> 6) & 1;
  const int m0 = blockIdx.y * 128, n0 = blockIdx.x * 128;
  const int li = lane & 15, lg = lane >> 4;
  const int rowA = t >> 2, kb8 = (t & 3) * 8;
  f32x4 acc[4][4] = {};
  for (int k0 = 0; k0 < K; k0 += 32) {
    __syncthreads();
    *(bfx8*)&As[rowA * 32 + kb8]        = *(const bfx8*)&A[(size_t)(m0 + rowA) * K + k0 + kb8];
    *(bfx8*)&As[(rowA + 64) * 32 + kb8] = *(const bfx8*)&A[(size_t)(m0 + rowA + 64) * K + k0 + kb8];
    *(bfx8*)&Bs[rowA * 32 + kb8]        = *(const bfx8*)&B[(size_t)(n0 + rowA) * K + k0 + kb8];
    *(bfx8*)&Bs[(rowA + 64) * 32 + kb8] = *(const bfx8*)&B[(size_t)(n0 + rowA + 64) * K + k0 + kb8];
    __syncthreads();
    bfx8 af[4], bf_[4];
#pragma unroll
    for (int mi = 0; mi < 4; mi++)
      af[mi] = *(const bfx8*)&As[(wm * 64 + mi * 16 + li) * 32 + lg * 8];
#pragma unroll
    for (int ni = 0; ni < 4; ni++)
      bf_[ni] = *(const bfx8*)&Bs[(wn * 64 + ni * 16 + li) * 32 + lg * 8];
#pragma unroll
    for (int mi = 0; mi < 4; mi++)
#pragma unroll
      for (int ni = 0; ni < 4; ni++)
        acc[mi][ni] = __builtin_amdgcn_mfma_f32_16x16x32_bf16(af[mi], bf_[ni], acc[mi][ni], 0, 0, 0);
  }
#pragma unroll
  for (int mi = 0; mi < 4; mi++) {
#pragma unroll
    for (int ni = 0; ni < 4; ni++) {
      const int nc  = n0 + wn * 64 + ni * 16 + li;
      const int mrb = m0 + wm * 64 + mi * 16 + lg * 4;
      if (EPI == 0) {
        const float bv = bias[nc];
#pragma unroll
        for (int r = 0; r < 4; r++)
          outf[(size_t)(mrb + r) * 512 + nc] = acc[mi][ni][r] + bv;
      } else {
        const int part = nc >> 9, within = nc & 511;
        const int h = within >> 6, d = within & 63;
        const int bb = mrb >> 11, ii = mrb & 2047;
        if (part == 0) {
#pragma unroll
          for (int r = 0; r < 4; r++)
            qb[(((size_t)bb * 8 + h) * 2048 + ii + r) * 64 + d] = f2bf(acc[mi][ni][r] * QSCALE);
        } else if (part == 1) {
#pragma unroll
          for (int r = 0; r < 4; r++)
            kb[(((size_t)bb * 8 + h) * 2048 + ii + r) * 64 + d] = f2bf(acc[mi][ni][r]);
        } else {
          ushort4 u;
          u.x = f2bf(acc[mi][ni][0]); u.y = f2bf(acc[mi][ni][1]);
          u.z = f2bf(acc[mi][ni][2]); u.w = f2bf(acc[mi][ni][3]);
          *(ushort4*)&vtb[(((size_t)bb * 8 + h) * 64 + d) * 2048 + ii] = u;
        }
      }
    }
  }
}

// ---------------- k2: softmax stats (m, l), j-split x2 ----------------
__global__ __launch_bounds__(256) void passA(
    const u16* __restrict__ qb, const u16* __restrict__ kb,
    float2* __restrict__ statp) {
  const int t = threadIdx.x, lane = t & 63, w = t >> 6;
  const int bh = blockIdx.y, js = blockIdx.z;
  const int i0 = blockIdx.x * 64 + w * 16;
  const int li = lane & 15, lg = lane >> 4;
  const u16* Qh = qb + ((size_t)bh * 2048 + i0 + li) * 64;
  const u16* Kb = kb + (size_t)bh * 2048 * 64;
  const bfx8 q0 = *(const bfx8*)&Qh[lg * 8];
  const bfx8 q1 = *(const bfx8*)&Qh[32 + lg * 8];
  float m = -1e30f, l = 0.f;
  const int jbeg = js * 1024, jend = jbeg + 1024;
  for (int j0 = jbeg; j0 < jend; j0 += 16) {
    const u16* Kh = Kb + (size_t)(j0 + li) * 64;
    bfx8 k0 = *(const bfx8*)&Kh[lg * 8];
    bfx8 k1 = *(const bfx8*)&Kh[32 + lg * 8];
    f32x4 s = {0.f, 0.f, 0.f, 0.f};
    s = __builtin_amdgcn_mfma_f32_16x16x32_bf16(k0, q0, s, 0, 0, 0);
    s = __builtin_amdgcn_mfma_f32_16x16x32_bf16(k1, q1, s, 0, 0, 0);
    float mt = fmaxf(fmaxf(s[0], s[1]), fmaxf(s[2], s[3]));
    float mn = fmaxf(m, mt);
    l = fmaf(l, exp2f(m - mn),
             exp2f(s[0] - mn) + exp2f(s[1] - mn) + exp2f(s[2] - mn) + exp2f(s[3] - mn));
    m = mn;
  }
  for (int off = 16; off < 64; off <<= 1) {
    float mo = __shfl_xor(m, off, 64);
    float lo = __shfl_xor(l, off, 64);
    float mn = fmaxf(m, mo);
    l = l * exp2f(m - mn) + lo * exp2f(mo - mn);
    m = mn;
  }
  if (lane < 16) statp[((size_t)js * 16 + bh) * 2048 + i0 + li] = make_float2(m, l);
}

// ---------------- k2b: merge the 2 j-split partials ----------------
__global__ __launch_bounds__(256) void mergeStats(
    const float2* __restrict__ statp, float2* __restrict__ stats) {
  int idx = blockIdx.x * 256 + threadIdx.x;  // bh*2048 + i
  float2 a = statp[idx], c = statp[32768 + idx];
  float m = fmaxf(a.x, c.x);
  float l = a.y * exp2f(a.x - m) + c.y * exp2f(c.x - m);
  stats[idx] = make_float2(m, 1.f / l);
}

// ---------------- k3: pass B — normalize, head-mix, LN, PV partial ----------------
// grid (128, 2, 2): x = i-tile-of-16, y = b, z = j-split. 512 thr = 8 waves.
__global__ __launch_bounds__(512) void passB(
    const u16* __restrict__ qb, const u16* __restrict__ kb,
    const u16* __restrict__ vtb, const float2* __restrict__ stats,
    const float* __restrict__ Wmix, const float* __restrict__ lng,
    const float* __restrict__ lnb, float* __restrict__ innerF) {
  __shared__ __align__(16) u16 A2[8 * 16 * 128];  // 32KB [g][i][j], j XOR-swizzled
  const int t = threadIdx.x, lane = t & 63, w = t >> 6;
  const int b = blockIdx.y, i0 = blockIdx.x * 16;
  const int li = lane & 15, lg = lane >> 4;
  const int swz = (li & 7) << 3;

  float wm_[8][8], lng_[8], lnb_[8];
#pragma unroll
  for (int h = 0; h < 8; h++)
#pragma unroll
    for (int g = 0; g < 8; g++) wm_[h][g] = Wmix[h * 8 + g];
#pragma unroll
  for (int g = 0; g < 8; g++) { lng_[g] = lng[g]; lnb_[g] = lnb[g]; }

  bfx8 qf[8][2];
  float2 st[8];
#pragma unroll
  for (int h = 0; h < 8; h++) {
    const u16* Qh = qb + (((size_t)(b * 8 + h)) * 2048 + i0 + li) * 64;
    qf[h][0] = *(const bfx8*)&Qh[lg * 8];
    qf[h][1] = *(const bfx8*)&Qh[32 + lg * 8];
    st[h] = stats[((size_t)(b * 8 + h)) * 2048 + i0 + li];
  }
  f32x4 pacc[4] = {};
  const int jmb = blockIdx.z * 1024;
  for (int jm = jmb; jm < jmb + 1024; jm += 128) {
    const int j0 = jm + w * 16;
    float p[8][4];
#pragma unroll
    for (int h = 0; h < 8; h++) {
      const u16* Kh = kb + (((size_t)(b * 8 + h)) * 2048 + j0 + li) * 64;
      bfx8 k0 = *(const bfx8*)&Kh[lg * 8];
      bfx8 k1 = *(const bfx8*)&Kh[32 + lg * 8];
      f32x4 s = {0.f, 0.f, 0.f, 0.f};
      s = __builtin_amdgcn_mfma_f32_16x16x32_bf16(k0, qf[h][0], s, 0, 0, 0);
      s = __builtin_amdgcn_mfma_f32_16x16x32_bf16(k1, qf[h][1], s, 0, 0, 0);
#pragma unroll
      for (int r = 0; r < 4; r++) p[h][r] = exp2f(s[r] - st[h].x) * st[h].y;
    }
    float av[8][4];
#pragma unroll
    for (int r = 0; r < 4; r++) {
      float a_[8]; float sum = 0.f, sumsq = 0.f;
#pragma unroll
      for (int g = 0; g < 8; g++) {
        float acc = 0.f;
#pragma unroll
        for (int h = 0; h < 8; h++) acc = fmaf(p[h][r], wm_[h][g], acc);
        a_[g] = acc; sum += acc; sumsq = fmaf(acc, acc, sumsq);
      }
      const float mu = sum * 0.125f;
      const float var = fmaf(sumsq, 0.125f, -mu * mu);
      const float rs = rsqrtf(var + 1e-5f);
#pragma unroll
      for (int g = 0; g < 8; g++)
        av[g][r] = fmaf((a_[g] - mu) * rs, lng_[g], lnb_[g]);
    }
    {
      const int jsw = (w * 16 + lg * 4) ^ swz;   // 4 consecutive j per lane
#pragma unroll
      for (int g = 0; g < 8; g++) {
        ushort4 u;
        u.x = f2bf(av[g][0]); u.y = f2bf(av[g][1]);
        u.z = f2bf(av[g][2]); u.w = f2bf(av[g][3]);
        *(ushort4*)&A2[(g * 16 + li) * 128 + jsw] = u;
      }
    }
    __syncthreads();
    {
      const u16* Vh = vtb + ((size_t)(b * 8 + w)) * 64 * 2048;
#pragma unroll
      for (int kc = 0; kc < 4; kc++) {
        const int jr = (kc * 32 + lg * 8) ^ swz;
        bfx8 af = *(const bfx8*)&A2[(w * 16 + li) * 128 + jr];
#pragma unroll
        for (int nd = 0; nd < 4; nd++) {
          bfx8 vf = *(const bfx8*)&Vh[(size_t)(nd * 16 + li) * 2048 + jm + kc * 32 + lg * 8];
          pacc[nd] = __builtin_amdgcn_mfma_f32_16x16x32_bf16(af, vf, pacc[nd], 0, 0, 0);
        }
      }
    }
    __syncthreads();
  }
#pragma unroll
  for (int nd = 0; nd < 4; nd++)
#pragma unroll
    for (int r = 0; r < 4; r++)
      atomicAdd(&innerF[((size_t)b * 2048 + i0 + lg * 4 + r) * 512 + w * 64 + nd * 16 + li],
                pacc[nd][r]);
}

// ---------------- k3b: inner f32 -> bf16 ----------------
__global__ __launch_bounds__(256) void convertInner(
    const float* __restrict__ inF, u16* __restrict__ outB) {
  int e = (blockIdx.x * 256 + threadIdx.x) * 4;
  float4 v = *(const float4*)&inF[e];
  ushort4 o; o.x = f2bf(v.x); o.y = f2bf(v.y); o.z = f2bf(v.z); o.w = f2bf(v.w);
  *(ushort4*)&outB[e] = o;
}

// ---------------- host ----------------
extern "C" void kernel_launch(void* const* d_in, const int* in_sizes, int n_in,
                              void* d_out, int out_size, void* d_ws, size_t ws_size,
                              hipStream_t stream) {
  const float* x      = (const float*)d_in[0];
  const float* w_qkv  = (const float*)d_in[1];
  const float* reattn = (const float*)d_in[2];
  const float* ln_g   = (const float*)d_in[3];
  const float* ln_b   = (const float*)d_in[4];
  const float* w_out  = (const float*)d_in[5];
  const float* b_out  = (const float*)d_in[6];
  float* out = (float*)d_out;
  char* ws = (char*)d_ws;
  // ws layout (bytes), total 22.3 MB:
  //  [0, 8388608)  : xb + wqb during k0/k1; then inner_f32 (zeroed after k1),
  //                  then innerB bf16 reuses qbf region after passB.
  u16*    xb    = (u16*)(ws + 0);
  u16*    wqb   = (u16*)(ws + 4194304);
  float*  innerF= (float*)(ws + 0);
  u16*    qbf   = (u16*)(ws + 8388608);    // [2,8,2048,64] bf16 (scaled)
  u16*    kbf   = (u16*)(ws + 12582912);   // [2,8,2048,64] bf16
  u16*    vtb   = (u16*)(ws + 16777216);   // [2,8,64,2048] bf16
  float2* stats = (float2*)(ws + 20971520);// [2,8,2048] (m, 1/l)
  float2* statp = (float2*)(ws + 21233664);// [2][2,8,2048] raw (m, l)
  u16*    wob   = (u16*)(ws + 21757952);   // 512x512 bf16
  u16*    innerB= (u16*)(ws + 8388608);    // reuses qbf after passB

  convert3<<<3072, 256, 0, stream>>>(x, w_qkv, w_out, xb, wqb, wob);
  gemm_k<1><<<dim3(12, 32), 256, 0, stream>>>(xb, wqb, 512, nullptr, nullptr, qbf, kbf, vtb);
  hipMemsetAsync(innerF, 0, 8388608, stream);
  passA<<<dim3(32, 16, 2), 256, 0, stream>>>(qbf, kbf, statp);
  mergeStats<<<128, 256, 0, stream>>>(statp, stats);
  passB<<<dim3(128, 2, 2), 512, 0, stream>>>(qbf, kbf, vtb, stats, reattn, ln_g, ln_b, innerF);
  convertInner<<<2048, 256, 0, stream>>>(innerF, innerB);
  gemm_k<0><<<dim3(4, 32), 256, 0, stream>>>(innerB, wob, 512, out, b_out, nullptr, nullptr, nullptr);
}

// Round 5
// 282.855 us; speedup vs baseline: 1.1176x; 1.0349x over previous
//
#include <hip/hip_runtime.h>
#include <hip/hip_bf16.h>

// DeepViT re-attention, fused flash-style two-pass.
//  k0 convert3 : x, w_qkv, w_out fp32 -> bf16 (ws)
//  k1 gemm<1>  : qkv = x @ w_qkv^T (bf16 MFMA); scatter q(scaled)/k/vT bf16
//  (memset)    : zero inner_f32 accumulator (reuses xb/wqb region)
//  k2 passA    : softmax stats (m, l) in exp2 domain, j-split x2
//  k2b merge   : combine j-split partials -> (m, 1/l)
//  k3 passB    : Q staged in LDS (frees 64 VGPRs -> 2 blocks/CU co-residency);
//                S', p, 8x8 head mix + LN in-lane, PV partial, atomicAdd f32.
//                grid (128,2,2)=512 blocks, 512 thr. NO min-occupancy hint
//                (R2/R3: (512,4) capped VGPR at 64 -> 250-320MB spill traffic).
//  k3b convert : inner_f32 -> bf16
//  k4 gemm<0>  : out = inner @ w_out^T + b_out (fp32)

typedef __attribute__((ext_vector_type(8))) short bfx8;
typedef __attribute__((ext_vector_type(4))) float f32x4;
typedef unsigned short u16;

#define QSCALE 0.18033688011112042f  /* (1/8) * log2(e) */

static __device__ inline u16 f2bf(float f) {
  union { float f; unsigned u; } cv; cv.f = f;
  unsigned u = cv.u;
  u += 0x7fffu + ((u >> 16) & 1u);   // RNE
  return (u16)(u >> 16);
}

// ---------------- k0: fp32 -> bf16 converts ----------------
__global__ __launch_bounds__(256) void convert3(
    const float* __restrict__ x, const float* __restrict__ wq,
    const float* __restrict__ wo,
    u16* __restrict__ xb, u16* __restrict__ wqb, u16* __restrict__ wob) {
  int e = (blockIdx.x * 256 + threadIdx.x) * 4;
  const float* src; u16* dst; int off;
  if (e < 2097152)      { src = x;  dst = xb;  off = e; }
  else if (e < 2883584) { src = wq; dst = wqb; off = e - 2097152; }
  else                  { src = wo; dst = wob; off = e - 2883584; }
  float4 v = *(const float4*)&src[off];
  ushort4 o; o.x = f2bf(v.x); o.y = f2bf(v.y); o.z = f2bf(v.z); o.w = f2bf(v.w);
  *(ushort4*)&dst[off] = o;
}

// ---------------- k1/k4: bf16 GEMM, C = A @ B^T ----------------
template<int EPI>
__global__ __launch_bounds__(256) void gemm_k(
    const u16* __restrict__ A, const u16* __restrict__ B, int K,
    float* __restrict__ outf, const float* __restrict__ bias,
    u16* __restrict__ qb, u16* __restrict__ kb, u16* __restrict__ vtb) {
  __shared__ u16 As[128 * 32];
  __shared__ u16 Bs[128 * 32];
  const int t = threadIdx.x, lane = t & 63;
  const int wm = (t >> 6) >> 1, wn = (t >> 6) & 1;
  const int m0 = blockIdx.y * 128, n0 = blockIdx.x * 128;
  const int li = lane & 15, lg = lane >> 4;
  const int rowA = t >> 2, kb8 = (t & 3) * 8;
  f32x4 acc[4][4] = {};
  for (int k0 = 0; k0 < K; k0 += 32) {
    __syncthreads();
    *(bfx8*)&As[rowA * 32 + kb8]        = *(const bfx8*)&A[(size_t)(m0 + rowA) * K + k0 + kb8];
    *(bfx8*)&As[(rowA + 64) * 32 + kb8] = *(const bfx8*)&A[(size_t)(m0 + rowA + 64) * K + k0 + kb8];
    *(bfx8*)&Bs[rowA * 32 + kb8]        = *(const bfx8*)&B[(size_t)(n0 + rowA) * K + k0 + kb8];
    *(bfx8*)&Bs[(rowA + 64) * 32 + kb8] = *(const bfx8*)&B[(size_t)(n0 + rowA + 64) * K + k0 + kb8];
    __syncthreads();
    bfx8 af[4], bf_[4];
#pragma unroll
    for (int mi = 0; mi < 4; mi++)
      af[mi] = *(const bfx8*)&As[(wm * 64 + mi * 16 + li) * 32 + lg * 8];
#pragma unroll
    for (int ni = 0; ni < 4; ni++)
      bf_[ni] = *(const bfx8*)&Bs[(wn * 64 + ni * 16 + li) * 32 + lg * 8];
#pragma unroll
    for (int mi = 0; mi < 4; mi++)
#pragma unroll
      for (int ni = 0; ni < 4; ni++)
        acc[mi][ni] = __builtin_amdgcn_mfma_f32_16x16x32_bf16(af[mi], bf_[ni], acc[mi][ni], 0, 0, 0);
  }
#pragma unroll
  for (int mi = 0; mi < 4; mi++) {
#pragma unroll
    for (int ni = 0; ni < 4; ni++) {
      const int nc  = n0 + wn * 64 + ni * 16 + li;
      const int mrb = m0 + wm * 64 + mi * 16 + lg * 4;
      if (EPI == 0) {
        const float bv = bias[nc];
#pragma unroll
        for (int r = 0; r < 4; r++)
          outf[(size_t)(mrb + r) * 512 + nc] = acc[mi][ni][r] + bv;
      } else {
        const int part = nc >> 9, within = nc & 511;
        const int h = within >> 6, d = within & 63;
        const int bb = mrb >> 11, ii = mrb & 2047;
        if (part == 0) {
#pragma unroll
          for (int r = 0; r < 4; r++)
            qb[(((size_t)bb * 8 + h) * 2048 + ii + r) * 64 + d] = f2bf(acc[mi][ni][r] * QSCALE);
        } else if (part == 1) {
#pragma unroll
          for (int r = 0; r < 4; r++)
            kb[(((size_t)bb * 8 + h) * 2048 + ii + r) * 64 + d] = f2bf(acc[mi][ni][r]);
        } else {
          ushort4 u;
          u.x = f2bf(acc[mi][ni][0]); u.y = f2bf(acc[mi][ni][1]);
          u.z = f2bf(acc[mi][ni][2]); u.w = f2bf(acc[mi][ni][3]);
          *(ushort4*)&vtb[(((size_t)bb * 8 + h) * 64 + d) * 2048 + ii] = u;
        }
      }
    }
  }
}

// ---------------- k2: softmax stats (m, l), j-split x2 ----------------
__global__ __launch_bounds__(256) void passA(
    const u16* __restrict__ qb, const u16* __restrict__ kb,
    float2* __restrict__ statp) {
  const int t = threadIdx.x, lane = t & 63, w = t >> 6;
  const int bh = blockIdx.y, js = blockIdx.z;
  const int i0 = blockIdx.x * 64 + w * 16;
  const int li = lane & 15, lg = lane >> 4;
  const u16* Qh = qb + ((size_t)bh * 2048 + i0 + li) * 64;
  const u16* Kb = kb + (size_t)bh * 2048 * 64;
  const bfx8 q0 = *(const bfx8*)&Qh[lg * 8];
  const bfx8 q1 = *(const bfx8*)&Qh[32 + lg * 8];
  float m = -1e30f, l = 0.f;
  const int jbeg = js * 1024, jend = jbeg + 1024;
  for (int j0 = jbeg; j0 < jend; j0 += 16) {
    const u16* Kh = Kb + (size_t)(j0 + li) * 64;
    bfx8 k0 = *(const bfx8*)&Kh[lg * 8];
    bfx8 k1 = *(const bfx8*)&Kh[32 + lg * 8];
    f32x4 s = {0.f, 0.f, 0.f, 0.f};
    s = __builtin_amdgcn_mfma_f32_16x16x32_bf16(k0, q0, s, 0, 0, 0);
    s = __builtin_amdgcn_mfma_f32_16x16x32_bf16(k1, q1, s, 0, 0, 0);
    float mt = fmaxf(fmaxf(s[0], s[1]), fmaxf(s[2], s[3]));
    float mn = fmaxf(m, mt);
    l = fmaf(l, exp2f(m - mn),
             exp2f(s[0] - mn) + exp2f(s[1] - mn) + exp2f(s[2] - mn) + exp2f(s[3] - mn));
    m = mn;
  }
  for (int off = 16; off < 64; off <<= 1) {
    float mo = __shfl_xor(m, off, 64);
    float lo = __shfl_xor(l, off, 64);
    float mn = fmaxf(m, mo);
    l = l * exp2f(m - mn) + lo * exp2f(mo - mn);
    m = mn;
  }
  if (lane < 16) statp[((size_t)js * 16 + bh) * 2048 + i0 + li] = make_float2(m, l);
}

// ---------------- k2b: merge the 2 j-split partials ----------------
__global__ __launch_bounds__(256) void mergeStats(
    const float2* __restrict__ statp, float2* __restrict__ stats) {
  int idx = blockIdx.x * 256 + threadIdx.x;  // bh*2048 + i
  float2 a = statp[idx], c = statp[32768 + idx];
  float m = fmaxf(a.x, c.x);
  float l = a.y * exp2f(a.x - m) + c.y * exp2f(c.x - m);
  stats[idx] = make_float2(m, 1.f / l);
}

// ---------------- k3: pass B — normalize, head-mix, LN, PV partial ----------------
// grid (128, 2, 2): x = i-tile-of-16, y = b, z = j-split. 512 thr = 8 waves.
// Q staged in LDS (row pad 64->72 shorts: lane reads hit 2-way banks = free),
// read back per jm-iteration -> persistent VGPRs ~96 -> 2 blocks/CU.
__global__ __launch_bounds__(512) void passB(
    const u16* __restrict__ qb, const u16* __restrict__ kb,
    const u16* __restrict__ vtb, const float2* __restrict__ stats,
    const float* __restrict__ Wmix, const float* __restrict__ lng,
    const float* __restrict__ lnb, float* __restrict__ innerF) {
  __shared__ __align__(16) u16 A2[8 * 16 * 128];  // 32KB [g][i][j], j XOR-swizzled
  __shared__ __align__(16) u16 Qs[8 * 16 * 72];   // 18KB [h][i][d], d-pad +8
  const int t = threadIdx.x, lane = t & 63, w = t >> 6;
  const int b = blockIdx.y, i0 = blockIdx.x * 16;
  const int li = lane & 15, lg = lane >> 4;
  const int swz = (li & 7) << 3;

  // stage Q: 1024 16B-chunks, 2 per thread
#pragma unroll
  for (int cc = 0; cc < 2; cc++) {
    const int c = t + cc * 512;
    const int h = c >> 7, qi = (c >> 3) & 15, d8 = c & 7;
    bfx8 v = *(const bfx8*)&qb[(((size_t)(b * 8 + h)) * 2048 + i0 + qi) * 64 + d8 * 8];
    *(bfx8*)&Qs[(h * 16 + qi) * 72 + d8 * 8] = v;
  }

  float wm_[8][8], lng_[8], lnb_[8];
#pragma unroll
  for (int h = 0; h < 8; h++)
#pragma unroll
    for (int g = 0; g < 8; g++) wm_[h][g] = Wmix[h * 8 + g];
#pragma unroll
  for (int g = 0; g < 8; g++) { lng_[g] = lng[g]; lnb_[g] = lnb[g]; }

  float2 st[8];
#pragma unroll
  for (int h = 0; h < 8; h++)
    st[h] = stats[((size_t)(b * 8 + h)) * 2048 + i0 + li];

  __syncthreads();  // Qs ready

  f32x4 pacc[4] = {};
  const int jmb = blockIdx.z * 1024;
  for (int jm = jmb; jm < jmb + 1024; jm += 128) {
    const int j0 = jm + w * 16;
    float p[8][4];
#pragma unroll
    for (int h = 0; h < 8; h++) {
      const u16* Kh = kb + (((size_t)(b * 8 + h)) * 2048 + j0 + li) * 64;
      bfx8 k0 = *(const bfx8*)&Kh[lg * 8];
      bfx8 k1 = *(const bfx8*)&Kh[32 + lg * 8];
      const bfx8 qA = *(const bfx8*)&Qs[(h * 16 + li) * 72 + lg * 8];
      const bfx8 qB = *(const bfx8*)&Qs[(h * 16 + li) * 72 + 32 + lg * 8];
      f32x4 s = {0.f, 0.f, 0.f, 0.f};
      s = __builtin_amdgcn_mfma_f32_16x16x32_bf16(k0, qA, s, 0, 0, 0);
      s = __builtin_amdgcn_mfma_f32_16x16x32_bf16(k1, qB, s, 0, 0, 0);
#pragma unroll
      for (int r = 0; r < 4; r++) p[h][r] = exp2f(s[r] - st[h].x) * st[h].y;
    }
    float av[8][4];
#pragma unroll
    for (int r = 0; r < 4; r++) {
      float a_[8]; float sum = 0.f, sumsq = 0.f;
#pragma unroll
      for (int g = 0; g < 8; g++) {
        float acc = 0.f;
#pragma unroll
        for (int h = 0; h < 8; h++) acc = fmaf(p[h][r], wm_[h][g], acc);
        a_[g] = acc; sum += acc; sumsq = fmaf(acc, acc, sumsq);
      }
      const float mu = sum * 0.125f;
      const float var = fmaf(sumsq, 0.125f, -mu * mu);
      const float rs = rsqrtf(var + 1e-5f);
#pragma unroll
      for (int g = 0; g < 8; g++)
        av[g][r] = fmaf((a_[g] - mu) * rs, lng_[g], lnb_[g]);
    }
    {
      const int jsw = (w * 16 + lg * 4) ^ swz;   // 4 consecutive j per lane
#pragma unroll
      for (int g = 0; g < 8; g++) {
        ushort4 u;
        u.x = f2bf(av[g][0]); u.y = f2bf(av[g][1]);
        u.z = f2bf(av[g][2]); u.w = f2bf(av[g][3]);
        *(ushort4*)&A2[(g * 16 + li) * 128 + jsw] = u;
      }
    }
    __syncthreads();
    {
      const u16* Vh = vtb + ((size_t)(b * 8 + w)) * 64 * 2048;
#pragma unroll
      for (int kc = 0; kc < 4; kc++) {
        const int jr = (kc * 32 + lg * 8) ^ swz;
        bfx8 af = *(const bfx8*)&A2[(w * 16 + li) * 128 + jr];
#pragma unroll
        for (int nd = 0; nd < 4; nd++) {
          bfx8 vf = *(const bfx8*)&Vh[(size_t)(nd * 16 + li) * 2048 + jm + kc * 32 + lg * 8];
          pacc[nd] = __builtin_amdgcn_mfma_f32_16x16x32_bf16(af, vf, pacc[nd], 0, 0, 0);
        }
      }
    }
    __syncthreads();
  }
#pragma unroll
  for (int nd = 0; nd < 4; nd++)
#pragma unroll
    for (int r = 0; r < 4; r++)
      atomicAdd(&innerF[((size_t)b * 2048 + i0 + lg * 4 + r) * 512 + w * 64 + nd * 16 + li],
                pacc[nd][r]);
}

// ---------------- k3b: inner f32 -> bf16 ----------------
__global__ __launch_bounds__(256) void convertInner(
    const float* __restrict__ inF, u16* __restrict__ outB) {
  int e = (blockIdx.x * 256 + threadIdx.x) * 4;
  float4 v = *(const float4*)&inF[e];
  ushort4 o; o.x = f2bf(v.x); o.y = f2bf(v.y); o.z = f2bf(v.z); o.w = f2bf(v.w);
  *(ushort4*)&outB[e] = o;
}

// ---------------- host ----------------
extern "C" void kernel_launch(void* const* d_in, const int* in_sizes, int n_in,
                              void* d_out, int out_size, void* d_ws, size_t ws_size,
                              hipStream_t stream) {
  const float* x      = (const float*)d_in[0];
  const float* w_qkv  = (const float*)d_in[1];
  const float* reattn = (const float*)d_in[2];
  const float* ln_g   = (const float*)d_in[3];
  const float* ln_b   = (const float*)d_in[4];
  const float* w_out  = (const float*)d_in[5];
  const float* b_out  = (const float*)d_in[6];
  float* out = (float*)d_out;
  char* ws = (char*)d_ws;
  // ws layout (bytes), total 22.3 MB:
  //  [0, 8388608)  : xb + wqb during k0/k1; then inner_f32 (zeroed after k1),
  //                  then innerB bf16 reuses qbf region after passB.
  u16*    xb    = (u16*)(ws + 0);
  u16*    wqb   = (u16*)(ws + 4194304);
  float*  innerF= (float*)(ws + 0);
  u16*    qbf   = (u16*)(ws + 8388608);    // [2,8,2048,64] bf16 (scaled)
  u16*    kbf   = (u16*)(ws + 12582912);   // [2,8,2048,64] bf16
  u16*    vtb   = (u16*)(ws + 16777216);   // [2,8,64,2048] bf16
  float2* stats = (float2*)(ws + 20971520);// [2,8,2048] (m, 1/l)
  float2* statp = (float2*)(ws + 21233664);// [2][2,8,2048] raw (m, l)
  u16*    wob   = (u16*)(ws + 21757952);   // 512x512 bf16
  u16*    innerB= (u16*)(ws + 8388608);    // reuses qbf after passB

  convert3<<<3072, 256, 0, stream>>>(x, w_qkv, w_out, xb, wqb, wob);
  gemm_k<1><<<dim3(12, 32), 256, 0, stream>>>(xb, wqb, 512, nullptr, nullptr, qbf, kbf, vtb);
  hipMemsetAsync(innerF, 0, 8388608, stream);
  passA<<<dim3(32, 16, 2), 256, 0, stream>>>(qbf, kbf, statp);
  mergeStats<<<128, 256, 0, stream>>>(statp, stats);
  passB<<<dim3(128, 2, 2), 512, 0, stream>>>(qbf, kbf, vtb, stats, reattn, ln_g, ln_b, innerF);
  convertInner<<<2048, 256, 0, stream>>>(innerF, innerB);
  gemm_k<0><<<dim3(4, 32), 256, 0, stream>>>(innerB, wob, 512, out, b_out, nullptr, nullptr, nullptr);
}

// Round 6
// 241.201 us; speedup vs baseline: 1.3106x; 1.1727x over previous
//
#include <hip/hip_runtime.h>
#include <hip/hip_bf16.h>

// DeepViT re-attention, fused flash-style two-pass.
//  k0 convert3 : x, w_qkv, w_out fp32 -> bf16 (ws)
//  k1 gemm<1>  : qkv = x @ w_qkv^T (bf16 MFMA); scatter q(scaled)/k/vT bf16
//  (memset)    : zero inner_f32 accumulator (reuses xb/wqb region)
//  k2 passA    : softmax stats (m, l) in exp2 domain, j-split x2
//  k2b merge   : combine partials -> single stat M = m + log2(l)
//  k3 passB    : Q staged in LDS; p = exp2(s - M); 8x8 head mix + LN in-lane
//                (packed bf16 accumulation, apk[8][2] u32); PV partial;
//                atomicAdd f32. Register budget target: arch <= 112 so that
//                arch + 16 AGPR (pacc) <= 128 -> 4 waves/SIMD -> 2 blocks/CU.
//                (R4/R5: 124/116 arch + 16 acc > 128 -> only 1 block/CU.)
//  k3b convert : inner_f32 -> bf16
//  k4 gemm<0>  : out = inner @ w_out^T + b_out (fp32)

typedef __attribute__((ext_vector_type(8))) short bfx8;
typedef __attribute__((ext_vector_type(4))) float f32x4;
typedef unsigned short u16;
typedef unsigned int u32;

#define QSCALE 0.18033688011112042f  /* (1/8) * log2(e) */

static __device__ inline u16 f2bf(float f) {
  union { float f; unsigned u; } cv; cv.f = f;
  unsigned u = cv.u;
  u += 0x7fffu + ((u >> 16) & 1u);   // RNE
  return (u16)(u >> 16);
}

// ---------------- k0: fp32 -> bf16 converts ----------------
__global__ __launch_bounds__(256) void convert3(
    const float* __restrict__ x, const float* __restrict__ wq,
    const float* __restrict__ wo,
    u16* __restrict__ xb, u16* __restrict__ wqb, u16* __restrict__ wob) {
  int e = (blockIdx.x * 256 + threadIdx.x) * 4;
  const float* src; u16* dst; int off;
  if (e < 2097152)      { src = x;  dst = xb;  off = e; }
  else if (e < 2883584) { src = wq; dst = wqb; off = e - 2097152; }
  else                  { src = wo; dst = wob; off = e - 2883584; }
  float4 v = *(const float4*)&src[off];
  ushort4 o; o.x = f2bf(v.x); o.y = f2bf(v.y); o.z = f2bf(v.z); o.w = f2bf(v.w);
  *(ushort4*)&dst[off] = o;
}

// ---------------- k1/k4: bf16 GEMM, C = A @ B^T ----------------
template<int EPI>
__global__ __launch_bounds__(256) void gemm_k(
    const u16* __restrict__ A, const u16* __restrict__ B, int K,
    float* __restrict__ outf, const float* __restrict__ bias,
    u16* __restrict__ qb, u16* __restrict__ kb, u16* __restrict__ vtb) {
  __shared__ u16 As[128 * 32];
  __shared__ u16 Bs[128 * 32];
  const int t = threadIdx.x, lane = t & 63;
  const int wm = (t >> 6) >> 1, wn = (t >> 6) & 1;
  const int m0 = blockIdx.y * 128, n0 = blockIdx.x * 128;
  const int li = lane & 15, lg = lane >> 4;
  const int rowA = t >> 2, kb8 = (t & 3) * 8;
  f32x4 acc[4][4] = {};
  for (int k0 = 0; k0 < K; k0 += 32) {
    __syncthreads();
    *(bfx8*)&As[rowA * 32 + kb8]        = *(const bfx8*)&A[(size_t)(m0 + rowA) * K + k0 + kb8];
    *(bfx8*)&As[(rowA + 64) * 32 + kb8] = *(const bfx8*)&A[(size_t)(m0 + rowA + 64) * K + k0 + kb8];
    *(bfx8*)&Bs[rowA * 32 + kb8]        = *(const bfx8*)&B[(size_t)(n0 + rowA) * K + k0 + kb8];
    *(bfx8*)&Bs[(rowA + 64) * 32 + kb8] = *(const bfx8*)&B[(size_t)(n0 + rowA + 64) * K + k0 + kb8];
    __syncthreads();
    bfx8 af[4], bf_[4];
#pragma unroll
    for (int mi = 0; mi < 4; mi++)
      af[mi] = *(const bfx8*)&As[(wm * 64 + mi * 16 + li) * 32 + lg * 8];
#pragma unroll
    for (int ni = 0; ni < 4; ni++)
      bf_[ni] = *(const bfx8*)&Bs[(wn * 64 + ni * 16 + li) * 32 + lg * 8];
#pragma unroll
    for (int mi = 0; mi < 4; mi++)
#pragma unroll
      for (int ni = 0; ni < 4; ni++)
        acc[mi][ni] = __builtin_amdgcn_mfma_f32_16x16x32_bf16(af[mi], bf_[ni], acc[mi][ni], 0, 0, 0);
  }
#pragma unroll
  for (int mi = 0; mi < 4; mi++) {
#pragma unroll
    for (int ni = 0; ni < 4; ni++) {
      const int nc  = n0 + wn * 64 + ni * 16 + li;
      const int mrb = m0 + wm * 64 + mi * 16 + lg * 4;
      if (EPI == 0) {
        const float bv = bias[nc];
#pragma unroll
        for (int r = 0; r < 4; r++)
          outf[(size_t)(mrb + r) * 512 + nc] = acc[mi][ni][r] + bv;
      } else {
        const int part = nc >> 9, within = nc & 511;
        const int h = within >> 6, d = within & 63;
        const int bb = mrb >> 11, ii = mrb & 2047;
        if (part == 0) {
#pragma unroll
          for (int r = 0; r < 4; r++)
            qb[(((size_t)bb * 8 + h) * 2048 + ii + r) * 64 + d] = f2bf(acc[mi][ni][r] * QSCALE);
        } else if (part == 1) {
#pragma unroll
          for (int r = 0; r < 4; r++)
            kb[(((size_t)bb * 8 + h) * 2048 + ii + r) * 64 + d] = f2bf(acc[mi][ni][r]);
        } else {
          ushort4 u;
          u.x = f2bf(acc[mi][ni][0]); u.y = f2bf(acc[mi][ni][1]);
          u.z = f2bf(acc[mi][ni][2]); u.w = f2bf(acc[mi][ni][3]);
          *(ushort4*)&vtb[(((size_t)bb * 8 + h) * 64 + d) * 2048 + ii] = u;
        }
      }
    }
  }
}

// ---------------- k2: softmax stats (m, l), j-split x2 ----------------
__global__ __launch_bounds__(256) void passA(
    const u16* __restrict__ qb, const u16* __restrict__ kb,
    float2* __restrict__ statp) {
  const int t = threadIdx.x, lane = t & 63, w = t >> 6;
  const int bh = blockIdx.y, js = blockIdx.z;
  const int i0 = blockIdx.x * 64 + w * 16;
  const int li = lane & 15, lg = lane >> 4;
  const u16* Qh = qb + ((size_t)bh * 2048 + i0 + li) * 64;
  const u16* Kb = kb + (size_t)bh * 2048 * 64;
  const bfx8 q0 = *(const bfx8*)&Qh[lg * 8];
  const bfx8 q1 = *(const bfx8*)&Qh[32 + lg * 8];
  float m = -1e30f, l = 0.f;
  const int jbeg = js * 1024, jend = jbeg + 1024;
  for (int j0 = jbeg; j0 < jend; j0 += 16) {
    const u16* Kh = Kb + (size_t)(j0 + li) * 64;
    bfx8 k0 = *(const bfx8*)&Kh[lg * 8];
    bfx8 k1 = *(const bfx8*)&Kh[32 + lg * 8];
    f32x4 s = {0.f, 0.f, 0.f, 0.f};
    s = __builtin_amdgcn_mfma_f32_16x16x32_bf16(k0, q0, s, 0, 0, 0);
    s = __builtin_amdgcn_mfma_f32_16x16x32_bf16(k1, q1, s, 0, 0, 0);
    float mt = fmaxf(fmaxf(s[0], s[1]), fmaxf(s[2], s[3]));
    float mn = fmaxf(m, mt);
    l = fmaf(l, exp2f(m - mn),
             exp2f(s[0] - mn) + exp2f(s[1] - mn) + exp2f(s[2] - mn) + exp2f(s[3] - mn));
    m = mn;
  }
  for (int off = 16; off < 64; off <<= 1) {
    float mo = __shfl_xor(m, off, 64);
    float lo = __shfl_xor(l, off, 64);
    float mn = fmaxf(m, mo);
    l = l * exp2f(m - mn) + lo * exp2f(mo - mn);
    m = mn;
  }
  if (lane < 16) statp[((size_t)js * 16 + bh) * 2048 + i0 + li] = make_float2(m, l);
}

// ---------------- k2b: merge partials -> M = m + log2(l) ----------------
__global__ __launch_bounds__(256) void mergeStats(
    const float2* __restrict__ statp, float* __restrict__ statM) {
  int idx = blockIdx.x * 256 + threadIdx.x;  // bh*2048 + i
  float2 a = statp[idx], c = statp[32768 + idx];
  float m = fmaxf(a.x, c.x);
  float l = a.y * exp2f(a.x - m) + c.y * exp2f(c.x - m);
  statM[idx] = m + log2f(l);
}

// ---------------- k3: pass B — normalize, head-mix, LN, PV partial ----------------
// grid (128, 2, 2): x = i-tile-of-16, y = b, z = j-split. 512 thr = 8 waves.
__global__ __launch_bounds__(512) void passB(
    const u16* __restrict__ qb, const u16* __restrict__ kb,
    const u16* __restrict__ vtb, const float* __restrict__ statM,
    const float* __restrict__ Wmix, const float* __restrict__ lng,
    const float* __restrict__ lnb, float* __restrict__ innerF) {
  __shared__ __align__(16) u16 A2[8 * 16 * 128];  // 32KB [g][i][j], j XOR-swizzled
  __shared__ __align__(16) u16 Qs[8 * 16 * 72];   // 18KB [h][i][d], d-pad +8
  const int t = threadIdx.x, lane = t & 63, w = t >> 6;
  const int b = blockIdx.y, i0 = blockIdx.x * 16;
  const int li = lane & 15, lg = lane >> 4;
  const int swz = (li & 7) << 3;

  // stage Q: 1024 16B-chunks, 2 per thread
#pragma unroll
  for (int cc = 0; cc < 2; cc++) {
    const int c = t + cc * 512;
    const int h = c >> 7, qi = (c >> 3) & 15, d8 = c & 7;
    bfx8 v = *(const bfx8*)&qb[(((size_t)(b * 8 + h)) * 2048 + i0 + qi) * 64 + d8 * 8];
    *(bfx8*)&Qs[(h * 16 + qi) * 72 + d8 * 8] = v;
  }

  float wm_[8][8], lng_[8], lnb_[8];
#pragma unroll
  for (int h = 0; h < 8; h++)
#pragma unroll
    for (int g = 0; g < 8; g++) wm_[h][g] = Wmix[h * 8 + g];
#pragma unroll
  for (int g = 0; g < 8; g++) { lng_[g] = lng[g]; lnb_[g] = lnb[g]; }

  float stM[8];
#pragma unroll
  for (int h = 0; h < 8; h++)
    stM[h] = statM[((size_t)(b * 8 + h)) * 2048 + i0 + li];

  __syncthreads();  // Qs ready

  f32x4 pacc[4] = {};
  const int jmb = blockIdx.z * 1024;
  for (int jm = jmb; jm < jmb + 1024; jm += 128) {
    const int j0 = jm + w * 16;
    float p[8][4];
#pragma unroll
    for (int h = 0; h < 8; h++) {
      const u16* Kh = kb + (((size_t)(b * 8 + h)) * 2048 + j0 + li) * 64;
      bfx8 k0 = *(const bfx8*)&Kh[lg * 8];
      bfx8 k1 = *(const bfx8*)&Kh[32 + lg * 8];
      const bfx8 qA = *(const bfx8*)&Qs[(h * 16 + li) * 72 + lg * 8];
      const bfx8 qB = *(const bfx8*)&Qs[(h * 16 + li) * 72 + 32 + lg * 8];
      f32x4 s = {0.f, 0.f, 0.f, 0.f};
      s = __builtin_amdgcn_mfma_f32_16x16x32_bf16(k0, qA, s, 0, 0, 0);
      s = __builtin_amdgcn_mfma_f32_16x16x32_bf16(k1, qB, s, 0, 0, 0);
#pragma unroll
      for (int r = 0; r < 4; r++) p[h][r] = exp2f(s[r] - stM[h]);
    }
    u32 apk[8][2];
#pragma unroll
    for (int r = 0; r < 4; r++) {
      float a_[8]; float sum = 0.f, sumsq = 0.f;
#pragma unroll
      for (int g = 0; g < 8; g++) {
        float acc = 0.f;
#pragma unroll
        for (int h = 0; h < 8; h++) acc = fmaf(p[h][r], wm_[h][g], acc);
        a_[g] = acc; sum += acc; sumsq = fmaf(acc, acc, sumsq);
      }
      const float mu = sum * 0.125f;
      const float var = fmaf(sumsq, 0.125f, -mu * mu);
      const float rs = rsqrtf(var + 1e-5f);
#pragma unroll
      for (int g = 0; g < 8; g++) {
        const u32 bv = f2bf(fmaf((a_[g] - mu) * rs, lng_[g], lnb_[g]));
        if (r & 1) apk[g][r >> 1] |= bv << 16;
        else       apk[g][r >> 1]  = bv;
      }
    }
    {
      const int jsw = (w * 16 + lg * 4) ^ swz;   // 4 consecutive j per lane
#pragma unroll
      for (int g = 0; g < 8; g++)
        *(uint2*)&A2[(g * 16 + li) * 128 + jsw] = make_uint2(apk[g][0], apk[g][1]);
    }
    __syncthreads();
    {
      const u16* Vh = vtb + ((size_t)(b * 8 + w)) * 64 * 2048;
#pragma unroll
      for (int kc = 0; kc < 4; kc++) {
        const int jr = (kc * 32 + lg * 8) ^ swz;
        bfx8 af = *(const bfx8*)&A2[(w * 16 + li) * 128 + jr];
#pragma unroll
        for (int nd = 0; nd < 4; nd++) {
          bfx8 vf = *(const bfx8*)&Vh[(size_t)(nd * 16 + li) * 2048 + jm + kc * 32 + lg * 8];
          pacc[nd] = __builtin_amdgcn_mfma_f32_16x16x32_bf16(af, vf, pacc[nd], 0, 0, 0);
        }
      }
    }
    __syncthreads();
  }
#pragma unroll
  for (int nd = 0; nd < 4; nd++)
#pragma unroll
    for (int r = 0; r < 4; r++)
      atomicAdd(&innerF[((size_t)b * 2048 + i0 + lg * 4 + r) * 512 + w * 64 + nd * 16 + li],
                pacc[nd][r]);
}

// ---------------- k3b: inner f32 -> bf16 ----------------
__global__ __launch_bounds__(256) void convertInner(
    const float* __restrict__ inF, u16* __restrict__ outB) {
  int e = (blockIdx.x * 256 + threadIdx.x) * 4;
  float4 v = *(const float4*)&inF[e];
  ushort4 o; o.x = f2bf(v.x); o.y = f2bf(v.y); o.z = f2bf(v.z); o.w = f2bf(v.w);
  *(ushort4*)&outB[e] = o;
}

// ---------------- host ----------------
extern "C" void kernel_launch(void* const* d_in, const int* in_sizes, int n_in,
                              void* d_out, int out_size, void* d_ws, size_t ws_size,
                              hipStream_t stream) {
  const float* x      = (const float*)d_in[0];
  const float* w_qkv  = (const float*)d_in[1];
  const float* reattn = (const float*)d_in[2];
  const float* ln_g   = (const float*)d_in[3];
  const float* ln_b   = (const float*)d_in[4];
  const float* w_out  = (const float*)d_in[5];
  const float* b_out  = (const float*)d_in[6];
  float* out = (float*)d_out;
  char* ws = (char*)d_ws;
  // ws layout (bytes), total 22.3 MB:
  //  [0, 8388608)  : xb + wqb during k0/k1; then inner_f32 (zeroed after k1),
  //                  then innerB bf16 reuses qbf region after passB.
  u16*    xb    = (u16*)(ws + 0);
  u16*    wqb   = (u16*)(ws + 4194304);
  float*  innerF= (float*)(ws + 0);
  u16*    qbf   = (u16*)(ws + 8388608);    // [2,8,2048,64] bf16 (scaled)
  u16*    kbf   = (u16*)(ws + 12582912);   // [2,8,2048,64] bf16
  u16*    vtb   = (u16*)(ws + 16777216);   // [2,8,64,2048] bf16
  float*  statM = (float*)(ws + 20971520); // [2,8,2048] M = m + log2(l)
  float2* statp = (float2*)(ws + 21233664);// [2][2,8,2048] raw (m, l)
  u16*    wob   = (u16*)(ws + 21757952);   // 512x512 bf16
  u16*    innerB= (u16*)(ws + 8388608);    // reuses qbf after passB

  convert3<<<3072, 256, 0, stream>>>(x, w_qkv, w_out, xb, wqb, wob);
  gemm_k<1><<<dim3(12, 32), 256, 0, stream>>>(xb, wqb, 512, nullptr, nullptr, qbf, kbf, vtb);
  hipMemsetAsync(innerF, 0, 8388608, stream);
  passA<<<dim3(32, 16, 2), 256, 0, stream>>>(qbf, kbf, statp);
  mergeStats<<<128, 256, 0, stream>>>(statp, statM);
  passB<<<dim3(128, 2, 2), 512, 0, stream>>>(qbf, kbf, vtb, statM, reattn, ln_g, ln_b, innerF);
  convertInner<<<2048, 256, 0, stream>>>(innerF, innerB);
  gemm_k<0><<<dim3(4, 32), 256, 0, stream>>>(innerB, wob, 512, out, b_out, nullptr, nullptr, nullptr);
}

// Round 7
// 240.191 us; speedup vs baseline: 1.3161x; 1.0042x over previous
//
#include <hip/hip_runtime.h>
#include <hip/hip_bf16.h>

// DeepViT re-attention, fused flash-style two-pass.
//  k0 convert3 : x, w_qkv, w_out fp32 -> bf16 (ws)
//  k1 gemm<1>  : qkv = x @ w_qkv^T (bf16 MFMA); scatter q(scaled)/k/vT bf16
//  (memset)    : zero inner_f32 accumulator (reuses xb/wqb region)
//  k2 passA    : softmax stats (m, l) in exp2 domain, j-split x2
//  k3 passB    : fused stats-merge; Q staged in LDS; p = exp2(s - M);
//                8x8 head mix + LN in-lane (packed bf16); PV partial;
//                atomicAdd f32. waves_per_eu(4,4): budget 128 V+A per wave
//                (2 blocks/CU) but let arch go ~112 (R6: default squeezed
//                arch to 64 -> ILP collapse). Software prefetch h+1 / kc+1.
//  k3b convert : inner_f32 -> bf16
//  k4 gemm<0>  : out = inner @ w_out^T + b_out (fp32)

typedef __attribute__((ext_vector_type(8))) short bfx8;
typedef __attribute__((ext_vector_type(4))) float f32x4;
typedef unsigned short u16;
typedef unsigned int u32;

#define QSCALE 0.18033688011112042f  /* (1/8) * log2(e) */

static __device__ inline u16 f2bf(float f) {
  union { float f; unsigned u; } cv; cv.f = f;
  unsigned u = cv.u;
  u += 0x7fffu + ((u >> 16) & 1u);   // RNE
  return (u16)(u >> 16);
}

// ---------------- k0: fp32 -> bf16 converts ----------------
__global__ __launch_bounds__(256) void convert3(
    const float* __restrict__ x, const float* __restrict__ wq,
    const float* __restrict__ wo,
    u16* __restrict__ xb, u16* __restrict__ wqb, u16* __restrict__ wob) {
  int e = (blockIdx.x * 256 + threadIdx.x) * 4;
  const float* src; u16* dst; int off;
  if (e < 2097152)      { src = x;  dst = xb;  off = e; }
  else if (e < 2883584) { src = wq; dst = wqb; off = e - 2097152; }
  else                  { src = wo; dst = wob; off = e - 2883584; }
  float4 v = *(const float4*)&src[off];
  ushort4 o; o.x = f2bf(v.x); o.y = f2bf(v.y); o.z = f2bf(v.z); o.w = f2bf(v.w);
  *(ushort4*)&dst[off] = o;
}

// ---------------- k1/k4: bf16 GEMM, C = A @ B^T ----------------
template<int EPI>
__global__ __launch_bounds__(256) void gemm_k(
    const u16* __restrict__ A, const u16* __restrict__ B, int K,
    float* __restrict__ outf, const float* __restrict__ bias,
    u16* __restrict__ qb, u16* __restrict__ kb, u16* __restrict__ vtb) {
  __shared__ u16 As[128 * 32];
  __shared__ u16 Bs[128 * 32];
  const int t = threadIdx.x, lane = t & 63;
  const int wm = (t >> 6) >> 1, wn = (t >> 6) & 1;
  const int m0 = blockIdx.y * 128, n0 = blockIdx.x * 128;
  const int li = lane & 15, lg = lane >> 4;
  const int rowA = t >> 2, kb8 = (t & 3) * 8;
  f32x4 acc[4][4] = {};
  for (int k0 = 0; k0 < K; k0 += 32) {
    __syncthreads();
    *(bfx8*)&As[rowA * 32 + kb8]        = *(const bfx8*)&A[(size_t)(m0 + rowA) * K + k0 + kb8];
    *(bfx8*)&As[(rowA + 64) * 32 + kb8] = *(const bfx8*)&A[(size_t)(m0 + rowA + 64) * K + k0 + kb8];
    *(bfx8*)&Bs[rowA * 32 + kb8]        = *(const bfx8*)&B[(size_t)(n0 + rowA) * K + k0 + kb8];
    *(bfx8*)&Bs[(rowA + 64) * 32 + kb8] = *(const bfx8*)&B[(size_t)(n0 + rowA + 64) * K + k0 + kb8];
    __syncthreads();
    bfx8 af[4], bf_[4];
#pragma unroll
    for (int mi = 0; mi < 4; mi++)
      af[mi] = *(const bfx8*)&As[(wm * 64 + mi * 16 + li) * 32 + lg * 8];
#pragma unroll
    for (int ni = 0; ni < 4; ni++)
      bf_[ni] = *(const bfx8*)&Bs[(wn * 64 + ni * 16 + li) * 32 + lg * 8];
#pragma unroll
    for (int mi = 0; mi < 4; mi++)
#pragma unroll
      for (int ni = 0; ni < 4; ni++)
        acc[mi][ni] = __builtin_amdgcn_mfma_f32_16x16x32_bf16(af[mi], bf_[ni], acc[mi][ni], 0, 0, 0);
  }
#pragma unroll
  for (int mi = 0; mi < 4; mi++) {
#pragma unroll
    for (int ni = 0; ni < 4; ni++) {
      const int nc  = n0 + wn * 64 + ni * 16 + li;
      const int mrb = m0 + wm * 64 + mi * 16 + lg * 4;
      if (EPI == 0) {
        const float bv = bias[nc];
#pragma unroll
        for (int r = 0; r < 4; r++)
          outf[(size_t)(mrb + r) * 512 + nc] = acc[mi][ni][r] + bv;
      } else {
        const int part = nc >> 9, within = nc & 511;
        const int h = within >> 6, d = within & 63;
        const int bb = mrb >> 11, ii = mrb & 2047;
        if (part == 0) {
#pragma unroll
          for (int r = 0; r < 4; r++)
            qb[(((size_t)bb * 8 + h) * 2048 + ii + r) * 64 + d] = f2bf(acc[mi][ni][r] * QSCALE);
        } else if (part == 1) {
#pragma unroll
          for (int r = 0; r < 4; r++)
            kb[(((size_t)bb * 8 + h) * 2048 + ii + r) * 64 + d] = f2bf(acc[mi][ni][r]);
        } else {
          ushort4 u;
          u.x = f2bf(acc[mi][ni][0]); u.y = f2bf(acc[mi][ni][1]);
          u.z = f2bf(acc[mi][ni][2]); u.w = f2bf(acc[mi][ni][3]);
          *(ushort4*)&vtb[(((size_t)bb * 8 + h) * 64 + d) * 2048 + ii] = u;
        }
      }
    }
  }
}

// ---------------- k2: softmax stats (m, l), j-split x2 ----------------
__global__ __launch_bounds__(256) void passA(
    const u16* __restrict__ qb, const u16* __restrict__ kb,
    float2* __restrict__ statp) {
  const int t = threadIdx.x, lane = t & 63, w = t >> 6;
  const int bh = blockIdx.y, js = blockIdx.z;
  const int i0 = blockIdx.x * 64 + w * 16;
  const int li = lane & 15, lg = lane >> 4;
  const u16* Qh = qb + ((size_t)bh * 2048 + i0 + li) * 64;
  const u16* Kb = kb + (size_t)bh * 2048 * 64;
  const bfx8 q0 = *(const bfx8*)&Qh[lg * 8];
  const bfx8 q1 = *(const bfx8*)&Qh[32 + lg * 8];
  float m = -1e30f, l = 0.f;
  const int jbeg = js * 1024, jend = jbeg + 1024;
  for (int j0 = jbeg; j0 < jend; j0 += 16) {
    const u16* Kh = Kb + (size_t)(j0 + li) * 64;
    bfx8 k0 = *(const bfx8*)&Kh[lg * 8];
    bfx8 k1 = *(const bfx8*)&Kh[32 + lg * 8];
    f32x4 s = {0.f, 0.f, 0.f, 0.f};
    s = __builtin_amdgcn_mfma_f32_16x16x32_bf16(k0, q0, s, 0, 0, 0);
    s = __builtin_amdgcn_mfma_f32_16x16x32_bf16(k1, q1, s, 0, 0, 0);
    float mt = fmaxf(fmaxf(s[0], s[1]), fmaxf(s[2], s[3]));
    float mn = fmaxf(m, mt);
    l = fmaf(l, exp2f(m - mn),
             exp2f(s[0] - mn) + exp2f(s[1] - mn) + exp2f(s[2] - mn) + exp2f(s[3] - mn));
    m = mn;
  }
  for (int off = 16; off < 64; off <<= 1) {
    float mo = __shfl_xor(m, off, 64);
    float lo = __shfl_xor(l, off, 64);
    float mn = fmaxf(m, mo);
    l = l * exp2f(m - mn) + lo * exp2f(mo - mn);
    m = mn;
  }
  if (lane < 16) statp[((size_t)js * 16 + bh) * 2048 + i0 + li] = make_float2(m, l);
}

// ---------------- k3: pass B — merge stats, normalize, head-mix, LN, PV ----------------
// grid (128, 2, 2): x = i-tile-of-16, y = b, z = j-split. 512 thr = 8 waves.
__global__ __launch_bounds__(512) __attribute__((amdgpu_waves_per_eu(4, 4)))
void passB(
    const u16* __restrict__ qb, const u16* __restrict__ kb,
    const u16* __restrict__ vtb, const float2* __restrict__ statp,
    const float* __restrict__ Wmix, const float* __restrict__ lng,
    const float* __restrict__ lnb, float* __restrict__ innerF) {
  __shared__ __align__(16) u16 A2[8 * 16 * 128];  // 32KB [g][i][j], j XOR-swizzled
  __shared__ __align__(16) u16 Qs[8 * 16 * 72];   // 18KB [h][i][d], d-pad +8
  const int t = threadIdx.x, lane = t & 63, w = t >> 6;
  const int b = blockIdx.y, i0 = blockIdx.x * 16;
  const int li = lane & 15, lg = lane >> 4;
  const int swz = (li & 7) << 3;

  // stage Q: 1024 16B-chunks, 2 per thread
#pragma unroll
  for (int cc = 0; cc < 2; cc++) {
    const int c = t + cc * 512;
    const int h = c >> 7, qi = (c >> 3) & 15, d8 = c & 7;
    bfx8 v = *(const bfx8*)&qb[(((size_t)(b * 8 + h)) * 2048 + i0 + qi) * 64 + d8 * 8];
    *(bfx8*)&Qs[(h * 16 + qi) * 72 + d8 * 8] = v;
  }

  float wm_[8][8], lng_[8], lnb_[8];
#pragma unroll
  for (int h = 0; h < 8; h++)
#pragma unroll
    for (int g = 0; g < 8; g++) wm_[h][g] = Wmix[h * 8 + g];
#pragma unroll
  for (int g = 0; g < 8; g++) { lng_[g] = lng[g]; lnb_[g] = lnb[g]; }

  // fused stats merge: M = m + log2(l) from the 2 j-split partials
  float stM[8];
#pragma unroll
  for (int h = 0; h < 8; h++) {
    const size_t idx = ((size_t)(b * 8 + h)) * 2048 + i0 + li;
    const float2 a = statp[idx], c = statp[32768 + idx];
    const float m = fmaxf(a.x, c.x);
    stM[h] = m + log2f(a.y * exp2f(a.x - m) + c.y * exp2f(c.x - m));
  }

  __syncthreads();  // Qs ready

  f32x4 pacc[4] = {};
  const int jmb = blockIdx.z * 1024;
  const size_t hstride = (size_t)2048 * 64;
  for (int jm = jmb; jm < jmb + 1024; jm += 128) {
    const int j0 = jm + w * 16;
    float p[8][4];
    const u16* Kh0 = kb + ((size_t)(b * 8) * 2048 + j0 + li) * 64;
    // software pipeline: K loads for h+1 issued before computing h
    bfx8 kc0 = *(const bfx8*)&Kh0[lg * 8];
    bfx8 kc1 = *(const bfx8*)&Kh0[32 + lg * 8];
#pragma unroll
    for (int h = 0; h < 8; h++) {
      bfx8 kn0, kn1;
      if (h < 7) {
        const u16* Khn = Kh0 + (h + 1) * hstride;
        kn0 = *(const bfx8*)&Khn[lg * 8];
        kn1 = *(const bfx8*)&Khn[32 + lg * 8];
      }
      const bfx8 qA = *(const bfx8*)&Qs[(h * 16 + li) * 72 + lg * 8];
      const bfx8 qB = *(const bfx8*)&Qs[(h * 16 + li) * 72 + 32 + lg * 8];
      f32x4 s = {0.f, 0.f, 0.f, 0.f};
      s = __builtin_amdgcn_mfma_f32_16x16x32_bf16(kc0, qA, s, 0, 0, 0);
      s = __builtin_amdgcn_mfma_f32_16x16x32_bf16(kc1, qB, s, 0, 0, 0);
#pragma unroll
      for (int r = 0; r < 4; r++) p[h][r] = exp2f(s[r] - stM[h]);
      kc0 = kn0; kc1 = kn1;
    }
    u32 apk[8][2];
#pragma unroll
    for (int r = 0; r < 4; r++) {
      float a_[8]; float sum = 0.f, sumsq = 0.f;
#pragma unroll
      for (int g = 0; g < 8; g++) {
        float acc = 0.f;
#pragma unroll
        for (int h = 0; h < 8; h++) acc = fmaf(p[h][r], wm_[h][g], acc);
        a_[g] = acc; sum += acc; sumsq = fmaf(acc, acc, sumsq);
      }
      const float mu = sum * 0.125f;
      const float var = fmaf(sumsq, 0.125f, -mu * mu);
      const float rs = rsqrtf(var + 1e-5f);
#pragma unroll
      for (int g = 0; g < 8; g++) {
        const u32 bv = f2bf(fmaf((a_[g] - mu) * rs, lng_[g], lnb_[g]));
        if (r & 1) apk[g][r >> 1] |= bv << 16;
        else       apk[g][r >> 1]  = bv;
      }
    }
    {
      const int jsw = (w * 16 + lg * 4) ^ swz;   // 4 consecutive j per lane
#pragma unroll
      for (int g = 0; g < 8; g++)
        *(uint2*)&A2[(g * 16 + li) * 128 + jsw] = make_uint2(apk[g][0], apk[g][1]);
    }
    __syncthreads();
    {
      const u16* Vh = vtb + ((size_t)(b * 8 + w)) * 64 * 2048;
      bfx8 af = *(const bfx8*)&A2[(w * 16 + li) * 128 + ((0 * 32 + lg * 8) ^ swz)];
      __builtin_amdgcn_s_setprio(1);
#pragma unroll
      for (int kc = 0; kc < 4; kc++) {
        bfx8 afn;
        if (kc < 3)
          afn = *(const bfx8*)&A2[(w * 16 + li) * 128 + (((kc + 1) * 32 + lg * 8) ^ swz)];
#pragma unroll
        for (int nd = 0; nd < 4; nd++) {
          bfx8 vf = *(const bfx8*)&Vh[(size_t)(nd * 16 + li) * 2048 + jm + kc * 32 + lg * 8];
          pacc[nd] = __builtin_amdgcn_mfma_f32_16x16x32_bf16(af, vf, pacc[nd], 0, 0, 0);
        }
        af = afn;
      }
      __builtin_amdgcn_s_setprio(0);
    }
    __syncthreads();
  }
#pragma unroll
  for (int nd = 0; nd < 4; nd++)
#pragma unroll
    for (int r = 0; r < 4; r++)
      atomicAdd(&innerF[((size_t)b * 2048 + i0 + lg * 4 + r) * 512 + w * 64 + nd * 16 + li],
                pacc[nd][r]);
}

// ---------------- k3b: inner f32 -> bf16 ----------------
__global__ __launch_bounds__(256) void convertInner(
    const float* __restrict__ inF, u16* __restrict__ outB) {
  int e = (blockIdx.x * 256 + threadIdx.x) * 4;
  float4 v = *(const float4*)&inF[e];
  ushort4 o; o.x = f2bf(v.x); o.y = f2bf(v.y); o.z = f2bf(v.z); o.w = f2bf(v.w);
  *(ushort4*)&outB[e] = o;
}

// ---------------- host ----------------
extern "C" void kernel_launch(void* const* d_in, const int* in_sizes, int n_in,
                              void* d_out, int out_size, void* d_ws, size_t ws_size,
                              hipStream_t stream) {
  const float* x      = (const float*)d_in[0];
  const float* w_qkv  = (const float*)d_in[1];
  const float* reattn = (const float*)d_in[2];
  const float* ln_g   = (const float*)d_in[3];
  const float* ln_b   = (const float*)d_in[4];
  const float* w_out  = (const float*)d_in[5];
  const float* b_out  = (const float*)d_in[6];
  float* out = (float*)d_out;
  char* ws = (char*)d_ws;
  // ws layout (bytes), total 22.3 MB:
  //  [0, 8388608)  : xb + wqb during k0/k1; then inner_f32 (zeroed after k1),
  //                  then innerB bf16 reuses qbf region after passB.
  u16*    xb    = (u16*)(ws + 0);
  u16*    wqb   = (u16*)(ws + 4194304);
  float*  innerF= (float*)(ws + 0);
  u16*    qbf   = (u16*)(ws + 8388608);    // [2,8,2048,64] bf16 (scaled)
  u16*    kbf   = (u16*)(ws + 12582912);   // [2,8,2048,64] bf16
  u16*    vtb   = (u16*)(ws + 16777216);   // [2,8,64,2048] bf16
  float2* statp = (float2*)(ws + 20971520);// [2][2,8,2048] raw (m, l)
  u16*    wob   = (u16*)(ws + 21757952);   // 512x512 bf16
  u16*    innerB= (u16*)(ws + 8388608);    // reuses qbf after passB

  convert3<<<3072, 256, 0, stream>>>(x, w_qkv, w_out, xb, wqb, wob);
  gemm_k<1><<<dim3(12, 32), 256, 0, stream>>>(xb, wqb, 512, nullptr, nullptr, qbf, kbf, vtb);
  hipMemsetAsync(innerF, 0, 8388608, stream);
  passA<<<dim3(32, 16, 2), 256, 0, stream>>>(qbf, kbf, statp);
  passB<<<dim3(128, 2, 2), 512, 0, stream>>>(qbf, kbf, vtb, statp, reattn, ln_g, ln_b, innerF);
  convertInner<<<2048, 256, 0, stream>>>(innerF, innerB);
  gemm_k<0><<<dim3(4, 32), 256, 0, stream>>>(innerB, wob, 512, out, b_out, nullptr, nullptr, nullptr);
}

// Round 8
// 229.203 us; speedup vs baseline: 1.3792x; 1.0479x over previous
//
#include <hip/hip_runtime.h>
#include <hip/hip_bf16.h>

// DeepViT re-attention, fused flash-style two-pass.
//  k0 convert3 : x, w_qkv, w_out fp32 -> bf16 (ws)
//  k1 gemm<1>  : qkv = x @ w_qkv^T (bf16 MFMA); scatter q(scaled)/k/vT bf16
//  k2 passA    : softmax stats (m, l) in exp2 domain, j-split x4, batched loads
//  k3 passB    : fused 4-way stats merge; Q in LDS; batched K loads
//                (+sched_barrier to stop the allocator serializing them);
//                pk-math mix+LN; v_cvt_pk_bf16_f32 packing; V batch-loaded
//                pre-barrier; PV; bf16 PARTIAL stores (no atomics/memset).
//  k4 gemm_out : out = (P0 + P1) @ w_out^T + b_out (fp32)

typedef __attribute__((ext_vector_type(8))) short bfx8;
typedef __attribute__((ext_vector_type(4))) float f32x4;
typedef __attribute__((ext_vector_type(2))) float f32x2;
typedef unsigned short u16;
typedef unsigned int u32;

#define QSCALE 0.18033688011112042f  /* (1/8) * log2(e) */

static __device__ inline u16 f2bf(float f) {
  union { float f; unsigned u; } cv; cv.f = f;
  unsigned u = cv.u;
  u += 0x7fffu + ((u >> 16) & 1u);   // RNE
  return (u16)(u >> 16);
}
static __device__ inline u32 cvtpk(float lo, float hi) {  // {bf16(lo), bf16(hi)}
  u32 d; asm("v_cvt_pk_bf16_f32 %0, %1, %2" : "=v"(d) : "v"(lo), "v"(hi)); return d;
}

// ---------------- k0: fp32 -> bf16 converts ----------------
__global__ __launch_bounds__(256) void convert3(
    const float* __restrict__ x, const float* __restrict__ wq,
    const float* __restrict__ wo,
    u16* __restrict__ xb, u16* __restrict__ wqb, u16* __restrict__ wob) {
  int e = (blockIdx.x * 256 + threadIdx.x) * 4;
  const float* src; u16* dst; int off;
  if (e < 2097152)      { src = x;  dst = xb;  off = e; }
  else if (e < 2883584) { src = wq; dst = wqb; off = e - 2097152; }
  else                  { src = wo; dst = wob; off = e - 2883584; }
  float4 v = *(const float4*)&src[off];
  ushort4 o; o.x = f2bf(v.x); o.y = f2bf(v.y); o.z = f2bf(v.z); o.w = f2bf(v.w);
  *(ushort4*)&dst[off] = o;
}

// ---------------- k1: bf16 GEMM, C = A @ B^T, QKV scatter epilogue ----------------
__global__ __launch_bounds__(256) void gemm_qkv(
    const u16* __restrict__ A, const u16* __restrict__ B,
    u16* __restrict__ qb, u16* __restrict__ kb, u16* __restrict__ vtb) {
  __shared__ u16 As[128 * 32];
  __shared__ u16 Bs[128 * 32];
  const int t = threadIdx.x, lane = t & 63;
  const int wm = (t >> 6) >> 1, wn = (t >> 6) & 1;
  const int m0 = blockIdx.y * 128, n0 = blockIdx.x * 128;
  const int li = lane & 15, lg = lane >> 4;
  const int rowA = t >> 2, kb8 = (t & 3) * 8;
  f32x4 acc[4][4] = {};
  for (int k0 = 0; k0 < 512; k0 += 32) {
    __syncthreads();
    *(bfx8*)&As[rowA * 32 + kb8]        = *(const bfx8*)&A[(size_t)(m0 + rowA) * 512 + k0 + kb8];
    *(bfx8*)&As[(rowA + 64) * 32 + kb8] = *(const bfx8*)&A[(size_t)(m0 + rowA + 64) * 512 + k0 + kb8];
    *(bfx8*)&Bs[rowA * 32 + kb8]        = *(const bfx8*)&B[(size_t)(n0 + rowA) * 512 + k0 + kb8];
    *(bfx8*)&Bs[(rowA + 64) * 32 + kb8] = *(const bfx8*)&B[(size_t)(n0 + rowA + 64) * 512 + k0 + kb8];
    __syncthreads();
    bfx8 af[4], bf_[4];
#pragma unroll
    for (int mi = 0; mi < 4; mi++)
      af[mi] = *(const bfx8*)&As[(wm * 64 + mi * 16 + li) * 32 + lg * 8];
#pragma unroll
    for (int ni = 0; ni < 4; ni++)
      bf_[ni] = *(const bfx8*)&Bs[(wn * 64 + ni * 16 + li) * 32 + lg * 8];
#pragma unroll
    for (int mi = 0; mi < 4; mi++)
#pragma unroll
      for (int ni = 0; ni < 4; ni++)
        acc[mi][ni] = __builtin_amdgcn_mfma_f32_16x16x32_bf16(af[mi], bf_[ni], acc[mi][ni], 0, 0, 0);
  }
#pragma unroll
  for (int mi = 0; mi < 4; mi++) {
#pragma unroll
    for (int ni = 0; ni < 4; ni++) {
      const int nc  = n0 + wn * 64 + ni * 16 + li;
      const int mrb = m0 + wm * 64 + mi * 16 + lg * 4;
      const int part = nc >> 9, within = nc & 511;
      const int h = within >> 6, d = within & 63;
      const int bb = mrb >> 11, ii = mrb & 2047;
      if (part == 0) {
#pragma unroll
        for (int r = 0; r < 4; r++)
          qb[(((size_t)bb * 8 + h) * 2048 + ii + r) * 64 + d] = f2bf(acc[mi][ni][r] * QSCALE);
      } else if (part == 1) {
#pragma unroll
        for (int r = 0; r < 4; r++)
          kb[(((size_t)bb * 8 + h) * 2048 + ii + r) * 64 + d] = f2bf(acc[mi][ni][r]);
      } else {
        ushort4 u;
        u.x = f2bf(acc[mi][ni][0]); u.y = f2bf(acc[mi][ni][1]);
        u.z = f2bf(acc[mi][ni][2]); u.w = f2bf(acc[mi][ni][3]);
        *(ushort4*)&vtb[(((size_t)bb * 8 + h) * 64 + d) * 2048 + ii] = u;
      }
    }
  }
}

// ---------------- k2: softmax stats (m, l), j-split x4, 2-tile batched ----------------
__global__ __launch_bounds__(256) void passA(
    const u16* __restrict__ qb, const u16* __restrict__ kb,
    float2* __restrict__ statp) {
  const int t = threadIdx.x, lane = t & 63, w = t >> 6;
  const int bh = blockIdx.y, js = blockIdx.z;
  const int i0 = blockIdx.x * 64 + w * 16;
  const int li = lane & 15, lg = lane >> 4;
  const u16* Qh = qb + ((size_t)bh * 2048 + i0 + li) * 64;
  const u16* Kb = kb + (size_t)bh * 2048 * 64;
  const bfx8 q0 = *(const bfx8*)&Qh[lg * 8];
  const bfx8 q1 = *(const bfx8*)&Qh[32 + lg * 8];
  float m = -1e30f, l = 0.f;
  const int jbeg = js * 512, jend = jbeg + 512;
  for (int j0 = jbeg; j0 < jend; j0 += 32) {
    const u16* KhA = Kb + (size_t)(j0 + li) * 64;
    const u16* KhB = KhA + 16 * 64;
    bfx8 a0 = *(const bfx8*)&KhA[lg * 8];
    bfx8 a1 = *(const bfx8*)&KhA[32 + lg * 8];
    bfx8 b0 = *(const bfx8*)&KhB[lg * 8];
    bfx8 b1 = *(const bfx8*)&KhB[32 + lg * 8];
    __builtin_amdgcn_sched_barrier(0);
    f32x4 sa = {0.f, 0.f, 0.f, 0.f}, sb = {0.f, 0.f, 0.f, 0.f};
    sa = __builtin_amdgcn_mfma_f32_16x16x32_bf16(a0, q0, sa, 0, 0, 0);
    sa = __builtin_amdgcn_mfma_f32_16x16x32_bf16(a1, q1, sa, 0, 0, 0);
    sb = __builtin_amdgcn_mfma_f32_16x16x32_bf16(b0, q0, sb, 0, 0, 0);
    sb = __builtin_amdgcn_mfma_f32_16x16x32_bf16(b1, q1, sb, 0, 0, 0);
    float mt = fmaxf(fmaxf(fmaxf(sa[0], sa[1]), fmaxf(sa[2], sa[3])),
                     fmaxf(fmaxf(sb[0], sb[1]), fmaxf(sb[2], sb[3])));
    float mn = fmaxf(m, mt);
    float es = (exp2f(sa[0] - mn) + exp2f(sa[1] - mn)) + (exp2f(sa[2] - mn) + exp2f(sa[3] - mn))
             + (exp2f(sb[0] - mn) + exp2f(sb[1] - mn)) + (exp2f(sb[2] - mn) + exp2f(sb[3] - mn));
    l = fmaf(l, exp2f(m - mn), es);
    m = mn;
  }
  for (int off = 16; off < 64; off <<= 1) {
    float mo = __shfl_xor(m, off, 64);
    float lo = __shfl_xor(l, off, 64);
    float mn = fmaxf(m, mo);
    l = l * exp2f(m - mn) + lo * exp2f(mo - mn);
    m = mn;
  }
  if (lane < 16) statp[(size_t)js * 32768 + (size_t)bh * 2048 + i0 + li] = make_float2(m, l);
}

// ---------------- k3: pass B ----------------
// grid (128, 2, 2): x = i-tile-of-16, y = b, z = j-half. 512 thr = 8 waves.
__global__ __launch_bounds__(512) __attribute__((amdgpu_waves_per_eu(4, 4)))
void passB(
    const u16* __restrict__ qb, const u16* __restrict__ kb,
    const u16* __restrict__ vtb, const float2* __restrict__ statp,
    const float* __restrict__ Wmix, const float* __restrict__ lng,
    const float* __restrict__ lnb, u16* __restrict__ innerP) {
  __shared__ __align__(16) u16 A2[8 * 16 * 128];  // 32KB [g][i][j], j XOR-swizzled
  __shared__ __align__(16) u16 Qs[8 * 16 * 72];   // 18KB [h][i][d], d-pad +8
  const int t = threadIdx.x, lane = t & 63, w = t >> 6;
  const int b = blockIdx.y, i0 = blockIdx.x * 16;
  const int li = lane & 15, lg = lane >> 4;
  const int swz = (li & 7) << 3;

  // stage Q: 1024 16B-chunks, 2 per thread
#pragma unroll
  for (int cc = 0; cc < 2; cc++) {
    const int c = t + cc * 512;
    const int h = c >> 7, qi = (c >> 3) & 15, d8 = c & 7;
    bfx8 v = *(const bfx8*)&qb[(((size_t)(b * 8 + h)) * 2048 + i0 + qi) * 64 + d8 * 8];
    *(bfx8*)&Qs[(h * 16 + qi) * 72 + d8 * 8] = v;
  }

  float wm_[8][8], lng_[8], lnb_[8];   // uniform -> SGPR
#pragma unroll
  for (int h = 0; h < 8; h++)
#pragma unroll
    for (int g = 0; g < 8; g++) wm_[h][g] = Wmix[h * 8 + g];
#pragma unroll
  for (int g = 0; g < 8; g++) { lng_[g] = lng[g]; lnb_[g] = lnb[g]; }

  // fused stats merge over 4 j-split partials: M = m + log2(l)
  float stM[8];
#pragma unroll
  for (int h = 0; h < 8; h++) {
    const size_t idx = ((size_t)(b * 8 + h)) * 2048 + i0 + li;
    float m = -1e30f, l = 0.f;
#pragma unroll
    for (int z = 0; z < 4; z++) {
      const float2 a = statp[(size_t)z * 32768 + idx];
      const float mn = fmaxf(m, a.x);
      l = l * exp2f(m - mn) + a.y * exp2f(a.x - mn);
      m = mn;
    }
    stM[h] = m + log2f(l);
  }

  __syncthreads();  // Qs ready

  f32x4 pacc[4] = {};
  const int jmb = blockIdx.z * 1024;
  const size_t hstr = (size_t)2048 * 64;
  for (int jm = jmb; jm < jmb + 1024; jm += 128) {
    const int j0 = jm + w * 16;
    const u16* Kb0 = kb + ((size_t)(b * 8) * 2048 + j0 + li) * 64;
    f32x2 p2[8][2];
    // 2 half-batches of 4 heads: 8 loads in flight, pinned by sched_barrier
#pragma unroll
    for (int hb = 0; hb < 2; hb++) {
      bfx8 kf[4][2];
#pragma unroll
      for (int hh = 0; hh < 4; hh++) {
        const u16* Kh = Kb0 + (size_t)(hb * 4 + hh) * hstr;
        kf[hh][0] = *(const bfx8*)&Kh[lg * 8];
        kf[hh][1] = *(const bfx8*)&Kh[32 + lg * 8];
      }
      __builtin_amdgcn_sched_barrier(0);
#pragma unroll
      for (int hh = 0; hh < 4; hh++) {
        const int h = hb * 4 + hh;
        const bfx8 qA = *(const bfx8*)&Qs[(h * 16 + li) * 72 + lg * 8];
        const bfx8 qB = *(const bfx8*)&Qs[(h * 16 + li) * 72 + 32 + lg * 8];
        f32x4 s = {0.f, 0.f, 0.f, 0.f};
        s = __builtin_amdgcn_mfma_f32_16x16x32_bf16(kf[hh][0], qA, s, 0, 0, 0);
        s = __builtin_amdgcn_mfma_f32_16x16x32_bf16(kf[hh][1], qB, s, 0, 0, 0);
        p2[h][0][0] = exp2f(s[0] - stM[h]);
        p2[h][0][1] = exp2f(s[1] - stM[h]);
        p2[h][1][0] = exp2f(s[2] - stM[h]);
        p2[h][1][1] = exp2f(s[3] - stM[h]);
      }
    }
    // 8x8 head mix + LN, packed f32x2 (v_pk_fma) + cvt_pk_bf16
    u32 apk[8][2];
#pragma unroll
    for (int rp = 0; rp < 2; rp++) {
      f32x2 a2[8];
      f32x2 sum = {0.f, 0.f}, sq = {0.f, 0.f};
#pragma unroll
      for (int g = 0; g < 8; g++) {
        f32x2 acc = {0.f, 0.f};
#pragma unroll
        for (int h = 0; h < 8; h++) {
          const f32x2 wmv = {wm_[h][g], wm_[h][g]};
          acc += p2[h][rp] * wmv;
        }
        a2[g] = acc; sum += acc; sq += acc * acc;
      }
      const f32x2 mu = sum * 0.125f;
      const f32x2 var = sq * 0.125f - mu * mu;
      f32x2 rs; rs[0] = rsqrtf(var[0] + 1e-5f); rs[1] = rsqrtf(var[1] + 1e-5f);
#pragma unroll
      for (int g = 0; g < 8; g++) {
        const f32x2 lg2 = {lng_[g], lng_[g]}, lb2 = {lnb_[g], lnb_[g]};
        const f32x2 av = (a2[g] - mu) * rs * lg2 + lb2;
        apk[g][rp] = cvtpk(av[0], av[1]);
      }
    }
    {
      const int jsw = (w * 16 + lg * 4) ^ swz;   // 4 consecutive j per lane
#pragma unroll
      for (int g = 0; g < 8; g++)
        *(uint2*)&A2[(g * 16 + li) * 128 + jsw] = make_uint2(apk[g][0], apk[g][1]);
    }
    // V batch loads issued BEFORE the barrier: latency hides under barrier drain
    const u16* Vh = vtb + ((size_t)(b * 8 + w)) * 64 * 2048 + jm;
    bfx8 vF[4][4];
#pragma unroll
    for (int kc = 0; kc < 4; kc++)
#pragma unroll
      for (int nd = 0; nd < 4; nd++)
        vF[kc][nd] = *(const bfx8*)&Vh[(size_t)(nd * 16 + li) * 2048 + kc * 32 + lg * 8];
    __syncthreads();
    __builtin_amdgcn_s_setprio(1);
#pragma unroll
    for (int kc = 0; kc < 4; kc++) {
      const bfx8 af = *(const bfx8*)&A2[(w * 16 + li) * 128 + ((kc * 32 + lg * 8) ^ swz)];
#pragma unroll
      for (int nd = 0; nd < 4; nd++)
        pacc[nd] = __builtin_amdgcn_mfma_f32_16x16x32_bf16(af, vF[kc][nd], pacc[nd], 0, 0, 0);
    }
    __builtin_amdgcn_s_setprio(0);
    __syncthreads();
  }
  // bf16 partial store (disjoint per z) — no atomics, no zeroing
  u16* dst = innerP + (size_t)blockIdx.z * 2097152 + ((size_t)b * 2048 + i0) * 512 + w * 64;
#pragma unroll
  for (int nd = 0; nd < 4; nd++)
#pragma unroll
    for (int r = 0; r < 4; r++)
      dst[(lg * 4 + r) * 512 + nd * 16 + li] = f2bf(pacc[nd][r]);
}

// ---------------- k4: out = (P0 + P1) @ wo^T + b_out ----------------
static __device__ inline bfx8 addbf8(bfx8 a, bfx8 b) {
  bfx8 r;
#pragma unroll
  for (int e = 0; e < 8; e++) {
    union { float f; u32 u; } fa, fb;
    fa.u = ((u32)(u16)a[e]) << 16;
    fb.u = ((u32)(u16)b[e]) << 16;
    r[e] = (short)f2bf(fa.f + fb.f);
  }
  return r;
}

__global__ __launch_bounds__(256) void gemm_out(
    const u16* __restrict__ A0, const u16* __restrict__ A1,
    const u16* __restrict__ B,
    float* __restrict__ outf, const float* __restrict__ bias) {
  __shared__ u16 As[128 * 32];
  __shared__ u16 Bs[128 * 32];
  const int t = threadIdx.x, lane = t & 63;
  const int wm = (t >> 6) >> 1, wn = (t >> 6) & 1;
  const int m0 = blockIdx.y * 128, n0 = blockIdx.x * 128;
  const int li = lane & 15, lg = lane >> 4;
  const int rowA = t >> 2, kb8 = (t & 3) * 8;
  f32x4 acc[4][4] = {};
  for (int k0 = 0; k0 < 512; k0 += 32) {
    __syncthreads();
    {
      const size_t iA = (size_t)(m0 + rowA) * 512 + k0 + kb8;
      const size_t iB = (size_t)(m0 + rowA + 64) * 512 + k0 + kb8;
      *(bfx8*)&As[rowA * 32 + kb8] =
          addbf8(*(const bfx8*)&A0[iA], *(const bfx8*)&A1[iA]);
      *(bfx8*)&As[(rowA + 64) * 32 + kb8] =
          addbf8(*(const bfx8*)&A0[iB], *(const bfx8*)&A1[iB]);
      *(bfx8*)&Bs[rowA * 32 + kb8]        = *(const bfx8*)&B[(size_t)(n0 + rowA) * 512 + k0 + kb8];
      *(bfx8*)&Bs[(rowA + 64) * 32 + kb8] = *(const bfx8*)&B[(size_t)(n0 + rowA + 64) * 512 + k0 + kb8];
    }
    __syncthreads();
    bfx8 af[4], bf_[4];
#pragma unroll
    for (int mi = 0; mi < 4; mi++)
      af[mi] = *(const bfx8*)&As[(wm * 64 + mi * 16 + li) * 32 + lg * 8];
#pragma unroll
    for (int ni = 0; ni < 4; ni++)
      bf_[ni] = *(const bfx8*)&Bs[(wn * 64 + ni * 16 + li) * 32 + lg * 8];
#pragma unroll
    for (int mi = 0; mi < 4; mi++)
#pragma unroll
      for (int ni = 0; ni < 4; ni++)
        acc[mi][ni] = __builtin_amdgcn_mfma_f32_16x16x32_bf16(af[mi], bf_[ni], acc[mi][ni], 0, 0, 0);
  }
#pragma unroll
  for (int mi = 0; mi < 4; mi++) {
#pragma unroll
    for (int ni = 0; ni < 4; ni++) {
      const int nc  = n0 + wn * 64 + ni * 16 + li;
      const int mrb = m0 + wm * 64 + mi * 16 + lg * 4;
      const float bv = bias[nc];
#pragma unroll
      for (int r = 0; r < 4; r++)
        outf[(size_t)(mrb + r) * 512 + nc] = acc[mi][ni][r] + bv;
    }
  }
}

// ---------------- host ----------------
extern "C" void kernel_launch(void* const* d_in, const int* in_sizes, int n_in,
                              void* d_out, int out_size, void* d_ws, size_t ws_size,
                              hipStream_t stream) {
  const float* x      = (const float*)d_in[0];
  const float* w_qkv  = (const float*)d_in[1];
  const float* reattn = (const float*)d_in[2];
  const float* ln_g   = (const float*)d_in[3];
  const float* ln_b   = (const float*)d_in[4];
  const float* w_out  = (const float*)d_in[5];
  const float* b_out  = (const float*)d_in[6];
  float* out = (float*)d_out;
  char* ws = (char*)d_ws;
  // ws layout (bytes), total ~21.5 MB:
  //  [0, 8388608)  : xb (0..4MB) + wqb (4..5.75MB) during k0/k1; after k1 the
  //                  region holds innerP: two bf16 partials of [2,2048,512]
  //                  at +0 and +4194304 (written by passB, read by gemm_out).
  u16*    xb    = (u16*)(ws + 0);
  u16*    wqb   = (u16*)(ws + 4194304);
  u16*    innerP= (u16*)(ws + 0);
  u16*    qbf   = (u16*)(ws + 8388608);    // [2,8,2048,64] bf16 (scaled)
  u16*    kbf   = (u16*)(ws + 12582912);   // [2,8,2048,64] bf16
  u16*    vtb   = (u16*)(ws + 16777216);   // [2,8,64,2048] bf16
  float2* statp = (float2*)(ws + 20971520);// [4][2,8,2048] raw (m, l) partials
  u16*    wob   = (u16*)(ws + 22020096);   // 512x512 bf16

  convert3<<<3072, 256, 0, stream>>>(x, w_qkv, w_out, xb, wqb, wob);
  gemm_qkv<<<dim3(12, 32), 256, 0, stream>>>(xb, wqb, qbf, kbf, vtb);
  passA<<<dim3(32, 16, 4), 256, 0, stream>>>(qbf, kbf, statp);
  passB<<<dim3(128, 2, 2), 512, 0, stream>>>(qbf, kbf, vtb, statp, reattn, ln_g, ln_b, innerP);
  gemm_out<<<dim3(4, 32), 256, 0, stream>>>(innerP, innerP + 2097152, wob, out, b_out);
}

// Round 9
// 227.900 us; speedup vs baseline: 1.3871x; 1.0057x over previous
//
#include <hip/hip_runtime.h>
#include <hip/hip_bf16.h>

// DeepViT re-attention, fused flash-style two-pass.
//  k0 convert3 : x, w_qkv, w_out fp32 -> bf16 (ws)
//  k1 gemm_qkv : qkv = x @ w_qkv^T (bf16 MFMA); scatter q(scaled)/k/vT bf16
//  k2 passA    : softmax stats (m, l), j-split x4, raw v_exp_f32
//  k3 passB    : fused 4-way stats merge; Q in LDS; batched K loads;
//                raw v_exp_f32 softmax (1 instr vs ~10 for __ocml exp2f);
//                scalar fmaf mix+LN; cvt_pk_bf16 packing; V batch pre-barrier;
//                PV; bf16 partial stores (disjoint per z).
//  k4 gemm_out : out = (P0 + P1) @ w_out^T + b_out (fp32)

typedef __attribute__((ext_vector_type(8))) short bfx8;
typedef __attribute__((ext_vector_type(4))) float f32x4;
typedef unsigned short u16;
typedef unsigned int u32;

#define QSCALE 0.18033688011112042f  /* (1/8) * log2(e) */

static __device__ inline u16 f2bf(float f) {
  union { float f; unsigned u; } cv; cv.f = f;
  unsigned u = cv.u;
  u += 0x7fffu + ((u >> 16) & 1u);   // RNE
  return (u16)(u >> 16);
}
static __device__ inline u32 cvtpk(float lo, float hi) {  // {bf16(lo), bf16(hi)}
  u32 d; asm("v_cvt_pk_bf16_f32 %0, %1, %2" : "=v"(d) : "v"(lo), "v"(hi)); return d;
}
static __device__ inline float fexp2(float x) {  // 2^x, 1 VALU instr
  float r; asm("v_exp_f32 %0, %1" : "=v"(r) : "v"(x)); return r;
}
static __device__ inline float flog2(float x) {  // log2(x), 1 VALU instr
  float r; asm("v_log_f32 %0, %1" : "=v"(r) : "v"(x)); return r;
}

// ---------------- k0: fp32 -> bf16 converts ----------------
__global__ __launch_bounds__(256) void convert3(
    const float* __restrict__ x, const float* __restrict__ wq,
    const float* __restrict__ wo,
    u16* __restrict__ xb, u16* __restrict__ wqb, u16* __restrict__ wob) {
  int e = (blockIdx.x * 256 + threadIdx.x) * 4;
  const float* src; u16* dst; int off;
  if (e < 2097152)      { src = x;  dst = xb;  off = e; }
  else if (e < 2883584) { src = wq; dst = wqb; off = e - 2097152; }
  else                  { src = wo; dst = wob; off = e - 2883584; }
  float4 v = *(const float4*)&src[off];
  ushort4 o; o.x = f2bf(v.x); o.y = f2bf(v.y); o.z = f2bf(v.z); o.w = f2bf(v.w);
  *(ushort4*)&dst[off] = o;
}

// ---------------- k1: bf16 GEMM, C = A @ B^T, QKV scatter epilogue ----------------
__global__ __launch_bounds__(256) void gemm_qkv(
    const u16* __restrict__ A, const u16* __restrict__ B,
    u16* __restrict__ qb, u16* __restrict__ kb, u16* __restrict__ vtb) {
  __shared__ u16 As[128 * 32];
  __shared__ u16 Bs[128 * 32];
  const int t = threadIdx.x, lane = t & 63;
  const int wm = (t >> 6) >> 1, wn = (t >> 6) & 1;
  const int m0 = blockIdx.y * 128, n0 = blockIdx.x * 128;
  const int li = lane & 15, lg = lane >> 4;
  const int rowA = t >> 2, kb8 = (t & 3) * 8;
  f32x4 acc[4][4] = {};
  for (int k0 = 0; k0 < 512; k0 += 32) {
    __syncthreads();
    *(bfx8*)&As[rowA * 32 + kb8]        = *(const bfx8*)&A[(size_t)(m0 + rowA) * 512 + k0 + kb8];
    *(bfx8*)&As[(rowA + 64) * 32 + kb8] = *(const bfx8*)&A[(size_t)(m0 + rowA + 64) * 512 + k0 + kb8];
    *(bfx8*)&Bs[rowA * 32 + kb8]        = *(const bfx8*)&B[(size_t)(n0 + rowA) * 512 + k0 + kb8];
    *(bfx8*)&Bs[(rowA + 64) * 32 + kb8] = *(const bfx8*)&B[(size_t)(n0 + rowA + 64) * 512 + k0 + kb8];
    __syncthreads();
    bfx8 af[4], bf_[4];
#pragma unroll
    for (int mi = 0; mi < 4; mi++)
      af[mi] = *(const bfx8*)&As[(wm * 64 + mi * 16 + li) * 32 + lg * 8];
#pragma unroll
    for (int ni = 0; ni < 4; ni++)
      bf_[ni] = *(const bfx8*)&Bs[(wn * 64 + ni * 16 + li) * 32 + lg * 8];
#pragma unroll
    for (int mi = 0; mi < 4; mi++)
#pragma unroll
      for (int ni = 0; ni < 4; ni++)
        acc[mi][ni] = __builtin_amdgcn_mfma_f32_16x16x32_bf16(af[mi], bf_[ni], acc[mi][ni], 0, 0, 0);
  }
#pragma unroll
  for (int mi = 0; mi < 4; mi++) {
#pragma unroll
    for (int ni = 0; ni < 4; ni++) {
      const int nc  = n0 + wn * 64 + ni * 16 + li;
      const int mrb = m0 + wm * 64 + mi * 16 + lg * 4;
      const int part = nc >> 9, within = nc & 511;
      const int h = within >> 6, d = within & 63;
      const int bb = mrb >> 11, ii = mrb & 2047;
      if (part == 0) {
#pragma unroll
        for (int r = 0; r < 4; r++)
          qb[(((size_t)bb * 8 + h) * 2048 + ii + r) * 64 + d] = f2bf(acc[mi][ni][r] * QSCALE);
      } else if (part == 1) {
#pragma unroll
        for (int r = 0; r < 4; r++)
          kb[(((size_t)bb * 8 + h) * 2048 + ii + r) * 64 + d] = f2bf(acc[mi][ni][r]);
      } else {
        ushort4 u;
        u.x = f2bf(acc[mi][ni][0]); u.y = f2bf(acc[mi][ni][1]);
        u.z = f2bf(acc[mi][ni][2]); u.w = f2bf(acc[mi][ni][3]);
        *(ushort4*)&vtb[(((size_t)bb * 8 + h) * 64 + d) * 2048 + ii] = u;
      }
    }
  }
}

// ---------------- k2: softmax stats (m, l), j-split x4, 2-tile batched ----------------
__global__ __launch_bounds__(256) void passA(
    const u16* __restrict__ qb, const u16* __restrict__ kb,
    float2* __restrict__ statp) {
  const int t = threadIdx.x, lane = t & 63, w = t >> 6;
  const int bh = blockIdx.y, js = blockIdx.z;
  const int i0 = blockIdx.x * 64 + w * 16;
  const int li = lane & 15, lg = lane >> 4;
  const u16* Qh = qb + ((size_t)bh * 2048 + i0 + li) * 64;
  const u16* Kb = kb + (size_t)bh * 2048 * 64;
  const bfx8 q0 = *(const bfx8*)&Qh[lg * 8];
  const bfx8 q1 = *(const bfx8*)&Qh[32 + lg * 8];
  float m = -1e30f, l = 0.f;
  const int jbeg = js * 512, jend = jbeg + 512;
  for (int j0 = jbeg; j0 < jend; j0 += 32) {
    const u16* KhA = Kb + (size_t)(j0 + li) * 64;
    const u16* KhB = KhA + 16 * 64;
    bfx8 a0 = *(const bfx8*)&KhA[lg * 8];
    bfx8 a1 = *(const bfx8*)&KhA[32 + lg * 8];
    bfx8 b0 = *(const bfx8*)&KhB[lg * 8];
    bfx8 b1 = *(const bfx8*)&KhB[32 + lg * 8];
    __builtin_amdgcn_sched_barrier(0);
    f32x4 sa = {0.f, 0.f, 0.f, 0.f}, sb = {0.f, 0.f, 0.f, 0.f};
    sa = __builtin_amdgcn_mfma_f32_16x16x32_bf16(a0, q0, sa, 0, 0, 0);
    sa = __builtin_amdgcn_mfma_f32_16x16x32_bf16(a1, q1, sa, 0, 0, 0);
    sb = __builtin_amdgcn_mfma_f32_16x16x32_bf16(b0, q0, sb, 0, 0, 0);
    sb = __builtin_amdgcn_mfma_f32_16x16x32_bf16(b1, q1, sb, 0, 0, 0);
    float mt = fmaxf(fmaxf(fmaxf(sa[0], sa[1]), fmaxf(sa[2], sa[3])),
                     fmaxf(fmaxf(sb[0], sb[1]), fmaxf(sb[2], sb[3])));
    float mn = fmaxf(m, mt);
    float es = (fexp2(sa[0] - mn) + fexp2(sa[1] - mn)) + (fexp2(sa[2] - mn) + fexp2(sa[3] - mn))
             + (fexp2(sb[0] - mn) + fexp2(sb[1] - mn)) + (fexp2(sb[2] - mn) + fexp2(sb[3] - mn));
    l = fmaf(l, fexp2(m - mn), es);
    m = mn;
  }
  for (int off = 16; off < 64; off <<= 1) {
    float mo = __shfl_xor(m, off, 64);
    float lo = __shfl_xor(l, off, 64);
    float mn = fmaxf(m, mo);
    l = l * fexp2(m - mn) + lo * fexp2(mo - mn);
    m = mn;
  }
  if (lane < 16) statp[(size_t)js * 32768 + (size_t)bh * 2048 + i0 + li] = make_float2(m, l);
}

// ---------------- k3: pass B ----------------
// grid (128, 2, 2): x = i-tile-of-16, y = b, z = j-half. 512 thr = 8 waves.
__global__ __launch_bounds__(512) __attribute__((amdgpu_waves_per_eu(4, 4)))
void passB(
    const u16* __restrict__ qb, const u16* __restrict__ kb,
    const u16* __restrict__ vtb, const float2* __restrict__ statp,
    const float* __restrict__ Wmix, const float* __restrict__ lng,
    const float* __restrict__ lnb, u16* __restrict__ innerP) {
  __shared__ __align__(16) u16 A2[8 * 16 * 128];  // 32KB [g][i][j], j XOR-swizzled
  __shared__ __align__(16) u16 Qs[8 * 16 * 72];   // 18KB [h][i][d], d-pad +8
  const int t = threadIdx.x, lane = t & 63, w = t >> 6;
  const int b = blockIdx.y, i0 = blockIdx.x * 16;
  const int li = lane & 15, lg = lane >> 4;
  const int swz = (li & 7) << 3;

  // stage Q: 1024 16B-chunks, 2 per thread
#pragma unroll
  for (int cc = 0; cc < 2; cc++) {
    const int c = t + cc * 512;
    const int h = c >> 7, qi = (c >> 3) & 15, d8 = c & 7;
    bfx8 v = *(const bfx8*)&qb[(((size_t)(b * 8 + h)) * 2048 + i0 + qi) * 64 + d8 * 8];
    *(bfx8*)&Qs[(h * 16 + qi) * 72 + d8 * 8] = v;
  }

  float wm_[8][8], lng_[8], lnb_[8];   // uniform -> SGPR
#pragma unroll
  for (int h = 0; h < 8; h++)
#pragma unroll
    for (int g = 0; g < 8; g++) wm_[h][g] = Wmix[h * 8 + g];
#pragma unroll
  for (int g = 0; g < 8; g++) { lng_[g] = lng[g]; lnb_[g] = lnb[g]; }

  // fused stats merge over 4 j-split partials: M = m + log2(l)
  float stM[8];
#pragma unroll
  for (int h = 0; h < 8; h++) {
    const size_t idx = ((size_t)(b * 8 + h)) * 2048 + i0 + li;
    float m = -1e30f, l = 0.f;
#pragma unroll
    for (int z = 0; z < 4; z++) {
      const float2 a = statp[(size_t)z * 32768 + idx];
      const float mn = fmaxf(m, a.x);
      l = l * fexp2(m - mn) + a.y * fexp2(a.x - mn);
      m = mn;
    }
    stM[h] = m + flog2(l);
  }

  __syncthreads();  // Qs ready

  f32x4 pacc[4] = {};
  const int jmb = blockIdx.z * 1024;
  const size_t hstr = (size_t)2048 * 64;
  for (int jm = jmb; jm < jmb + 1024; jm += 128) {
    const int j0 = jm + w * 16;
    const u16* Kb0 = kb + ((size_t)(b * 8) * 2048 + j0 + li) * 64;
    float p[8][4];
    // 2 half-batches of 4 heads: 8 loads in flight, pinned by sched_barrier
#pragma unroll
    for (int hb = 0; hb < 2; hb++) {
      bfx8 kf[4][2];
#pragma unroll
      for (int hh = 0; hh < 4; hh++) {
        const u16* Kh = Kb0 + (size_t)(hb * 4 + hh) * hstr;
        kf[hh][0] = *(const bfx8*)&Kh[lg * 8];
        kf[hh][1] = *(const bfx8*)&Kh[32 + lg * 8];
      }
      __builtin_amdgcn_sched_barrier(0);
#pragma unroll
      for (int hh = 0; hh < 4; hh++) {
        const int h = hb * 4 + hh;
        const bfx8 qA = *(const bfx8*)&Qs[(h * 16 + li) * 72 + lg * 8];
        const bfx8 qB = *(const bfx8*)&Qs[(h * 16 + li) * 72 + 32 + lg * 8];
        f32x4 s = {0.f, 0.f, 0.f, 0.f};
        s = __builtin_amdgcn_mfma_f32_16x16x32_bf16(kf[hh][0], qA, s, 0, 0, 0);
        s = __builtin_amdgcn_mfma_f32_16x16x32_bf16(kf[hh][1], qB, s, 0, 0, 0);
#pragma unroll
        for (int r = 0; r < 4; r++) p[h][r] = fexp2(s[r] - stM[h]);
      }
    }
    // 8x8 head mix + LN (scalar fmaf; 1 instr each) + cvt_pk packing
    u32 apk[8][2];
#pragma unroll
    for (int r = 0; r < 4; r++) {
      float a_[8]; float sum = 0.f, sumsq = 0.f;
#pragma unroll
      for (int g = 0; g < 8; g++) {
        float acc = 0.f;
#pragma unroll
        for (int h = 0; h < 8; h++) acc = fmaf(p[h][r], wm_[h][g], acc);
        a_[g] = acc; sum += acc; sumsq = fmaf(acc, acc, sumsq);
      }
      const float mu = sum * 0.125f;
      const float var = fmaf(sumsq, 0.125f, -mu * mu);
      const float rs = rsqrtf(var + 1e-5f);
#pragma unroll
      for (int g = 0; g < 8; g++) {
        const float av = fmaf((a_[g] - mu) * rs, lng_[g], lnb_[g]);
        if (r & 1) apk[g][r >> 1] |= cvtpk(av, av) & 0xffff0000u;
        else       apk[g][r >> 1]  = cvtpk(av, av) & 0x0000ffffu;
      }
    }
    {
      const int jsw = (w * 16 + lg * 4) ^ swz;   // 4 consecutive j per lane
#pragma unroll
      for (int g = 0; g < 8; g++)
        *(uint2*)&A2[(g * 16 + li) * 128 + jsw] = make_uint2(apk[g][0], apk[g][1]);
    }
    // V batch loads issued BEFORE the barrier: latency hides under barrier drain
    const u16* Vh = vtb + ((size_t)(b * 8 + w)) * 64 * 2048 + jm;
    bfx8 vF[4][4];
#pragma unroll
    for (int kc = 0; kc < 4; kc++)
#pragma unroll
      for (int nd = 0; nd < 4; nd++)
        vF[kc][nd] = *(const bfx8*)&Vh[(size_t)(nd * 16 + li) * 2048 + kc * 32 + lg * 8];
    __syncthreads();
    __builtin_amdgcn_s_setprio(1);
#pragma unroll
    for (int kc = 0; kc < 4; kc++) {
      const bfx8 af = *(const bfx8*)&A2[(w * 16 + li) * 128 + ((kc * 32 + lg * 8) ^ swz)];
#pragma unroll
      for (int nd = 0; nd < 4; nd++)
        pacc[nd] = __builtin_amdgcn_mfma_f32_16x16x32_bf16(af, vF[kc][nd], pacc[nd], 0, 0, 0);
    }
    __builtin_amdgcn_s_setprio(0);
    __syncthreads();
  }
  // bf16 partial store (disjoint per z) — no atomics, no zeroing
  u16* dst = innerP + (size_t)blockIdx.z * 2097152 + ((size_t)b * 2048 + i0) * 512 + w * 64;
#pragma unroll
  for (int nd = 0; nd < 4; nd++)
#pragma unroll
    for (int r = 0; r < 4; r++)
      dst[(lg * 4 + r) * 512 + nd * 16 + li] = f2bf(pacc[nd][r]);
}

// ---------------- k4: out = (P0 + P1) @ wo^T + b_out ----------------
static __device__ inline bfx8 addbf8(bfx8 a, bfx8 b) {
  bfx8 r;
#pragma unroll
  for (int e = 0; e < 8; e += 2) {
    union { float f; u32 u; } a0, a1, b0, b1;
    a0.u = ((u32)(u16)a[e]) << 16;     b0.u = ((u32)(u16)b[e]) << 16;
    a1.u = ((u32)(u16)a[e + 1]) << 16; b1.u = ((u32)(u16)b[e + 1]) << 16;
    const u32 pk = cvtpk(a0.f + b0.f, a1.f + b1.f);
    r[e] = (short)(pk & 0xffff); r[e + 1] = (short)(pk >> 16);
  }
  return r;
}

__global__ __launch_bounds__(256) void gemm_out(
    const u16* __restrict__ A0, const u16* __restrict__ A1,
    const u16* __restrict__ B,
    float* __restrict__ outf, const float* __restrict__ bias) {
  __shared__ u16 As[128 * 32];
  __shared__ u16 Bs[128 * 32];
  const int t = threadIdx.x, lane = t & 63;
  const int wm = (t >> 6) >> 1, wn = (t >> 6) & 1;
  const int m0 = blockIdx.y * 128, n0 = blockIdx.x * 128;
  const int li = lane & 15, lg = lane >> 4;
  const int rowA = t >> 2, kb8 = (t & 3) * 8;
  f32x4 acc[4][4] = {};
  for (int k0 = 0; k0 < 512; k0 += 32) {
    __syncthreads();
    {
      const size_t iA = (size_t)(m0 + rowA) * 512 + k0 + kb8;
      const size_t iB = (size_t)(m0 + rowA + 64) * 512 + k0 + kb8;
      *(bfx8*)&As[rowA * 32 + kb8] =
          addbf8(*(const bfx8*)&A0[iA], *(const bfx8*)&A1[iA]);
      *(bfx8*)&As[(rowA + 64) * 32 + kb8] =
          addbf8(*(const bfx8*)&A0[iB], *(const bfx8*)&A1[iB]);
      *(bfx8*)&Bs[rowA * 32 + kb8]        = *(const bfx8*)&B[(size_t)(n0 + rowA) * 512 + k0 + kb8];
      *(bfx8*)&Bs[(rowA + 64) * 32 + kb8] = *(const bfx8*)&B[(size_t)(n0 + rowA + 64) * 512 + k0 + kb8];
    }
    __syncthreads();
    bfx8 af[4], bf_[4];
#pragma unroll
    for (int mi = 0; mi < 4; mi++)
      af[mi] = *(const bfx8*)&As[(wm * 64 + mi * 16 + li) * 32 + lg * 8];
#pragma unroll
    for (int ni = 0; ni < 4; ni++)
      bf_[ni] = *(const bfx8*)&Bs[(wn * 64 + ni * 16 + li) * 32 + lg * 8];
#pragma unroll
    for (int mi = 0; mi < 4; mi++)
#pragma unroll
      for (int ni = 0; ni < 4; ni++)
        acc[mi][ni] = __builtin_amdgcn_mfma_f32_16x16x32_bf16(af[mi], bf_[ni], acc[mi][ni], 0, 0, 0);
  }
#pragma unroll
  for (int mi = 0; mi < 4; mi++) {
#pragma unroll
    for (int ni = 0; ni < 4; ni++) {
      const int nc  = n0 + wn * 64 + ni * 16 + li;
      const int mrb = m0 + wm * 64 + mi * 16 + lg * 4;
      const float bv = bias[nc];
#pragma unroll
      for (int r = 0; r < 4; r++)
        outf[(size_t)(mrb + r) * 512 + nc] = acc[mi][ni][r] + bv;
    }
  }
}

// ---------------- host ----------------
extern "C" void kernel_launch(void* const* d_in, const int* in_sizes, int n_in,
                              void* d_out, int out_size, void* d_ws, size_t ws_size,
                              hipStream_t stream) {
  const float* x      = (const float*)d_in[0];
  const float* w_qkv  = (const float*)d_in[1];
  const float* reattn = (const float*)d_in[2];
  const float* ln_g   = (const float*)d_in[3];
  const float* ln_b   = (const float*)d_in[4];
  const float* w_out  = (const float*)d_in[5];
  const float* b_out  = (const float*)d_in[6];
  float* out = (float*)d_out;
  char* ws = (char*)d_ws;
  // ws layout (bytes), total ~21.5 MB:
  //  [0, 8388608)  : xb + wqb during k0/k1; then innerP bf16 partials x2.
  u16*    xb    = (u16*)(ws + 0);
  u16*    wqb   = (u16*)(ws + 4194304);
  u16*    innerP= (u16*)(ws + 0);
  u16*    qbf   = (u16*)(ws + 8388608);    // [2,8,2048,64] bf16 (scaled)
  u16*    kbf   = (u16*)(ws + 12582912);   // [2,8,2048,64] bf16
  u16*    vtb   = (u16*)(ws + 16777216);   // [2,8,64,2048] bf16
  float2* statp = (float2*)(ws + 20971520);// [4][2,8,2048] raw (m, l) partials
  u16*    wob   = (u16*)(ws + 22020096);   // 512x512 bf16

  convert3<<<3072, 256, 0, stream>>>(x, w_qkv, w_out, xb, wqb, wob);
  gemm_qkv<<<dim3(12, 32), 256, 0, stream>>>(xb, wqb, qbf, kbf, vtb);
  passA<<<dim3(32, 16, 4), 256, 0, stream>>>(qbf, kbf, statp);
  passB<<<dim3(128, 2, 2), 512, 0, stream>>>(qbf, kbf, vtb, statp, reattn, ln_g, ln_b, innerP);
  gemm_out<<<dim3(4, 32), 256, 0, stream>>>(innerP, innerP + 2097152, wob, out, b_out);
}